// Round 14
// baseline (112.211 us; speedup 1.0000x reference)
//
#include <hip/hip_runtime.h>
#include <hip/hip_bf16.h>
#include <cmath>

#define CDIM 384
#define NB 8
#define NPIX 1024

typedef __attribute__((ext_vector_type(8))) short short8v;
typedef __attribute__((ext_vector_type(4))) float float4v;

__device__ __forceinline__ ushort f2bf(float f) {
  union { float f; unsigned u; } v; v.f = f;
  unsigned r = (v.u + 0x7fffu + ((v.u >> 16) & 1u)) >> 16;
  return (ushort)r;
}
__device__ __forceinline__ float bf2f(ushort u) {
  union { unsigned u; float f; } v; v.u = ((unsigned)u) << 16;
  return v.f;
}

// ---------------------------------------------------------------------------
// Kernel 0 (merged): blocks 0..19 bf16 twiddle tables; 20..163 projection
// weights -> bf16; 164..931 x (b,n,c) f32 -> xc (b,c,n) bf16 transpose.
// ---------------------------------------------------------------------------
__global__ __launch_bounds__(256) void prep_k(
    ushort* __restrict__ tbl,
    const float* __restrict__ wq, const float* __restrict__ wk,
    const float* __restrict__ wv, const float* __restrict__ wo,
    ushort* __restrict__ wqb, ushort* __restrict__ wkb,
    ushort* __restrict__ wvb, ushort* __restrict__ wob,
    const float* __restrict__ x, ushort* __restrict__ xc)
{
  __shared__ ushort T[128][33];
  if (blockIdx.x < 20) {
    int i = blockIdx.x * 256 + threadIdx.x;
    if (i >= 5 * 1024) return;
    int t = i >> 10, j = i & 1023, r = j >> 5, cidx = j & 31;
    float ang = (float)((r * cidx) & 31) * 0.19634954084936207f;
    float val;
    if (t == 0) val = cosf(ang);
    else if (t == 1) val = sinf(ang);
    else if (t == 2) val = -sinf(ang);
    else {
      if (cidx > 16) val = 0.f;
      else {
        float cv = (cidx == 0 || cidx == 16) ? 1.f : 2.f;
        val = (t == 3) ? cv * cosf(ang) : -cv * sinf(ang);
      }
    }
    tbl[i] = f2bf(val);
  } else if (blockIdx.x < 164) {
    int i = (blockIdx.x - 20) * 256 + threadIdx.x;
    if (i * 4 >= CDIM * CDIM) return;
    float4 va = *(const float4*)&wq[i * 4];
    float4 vb = *(const float4*)&wk[i * 4];
    float4 vc = *(const float4*)&wv[i * 4];
    float4 vd = *(const float4*)&wo[i * 4];
    ushort4 ra = { f2bf(va.x), f2bf(va.y), f2bf(va.z), f2bf(va.w) };
    ushort4 rb = { f2bf(vb.x), f2bf(vb.y), f2bf(vb.z), f2bf(vb.w) };
    ushort4 rc = { f2bf(vc.x), f2bf(vc.y), f2bf(vc.z), f2bf(vc.w) };
    ushort4 rd = { f2bf(vd.x), f2bf(vd.y), f2bf(vd.z), f2bf(vd.w) };
    *(ushort4*)&wqb[i * 4] = ra;
    *(ushort4*)&wkb[i * 4] = rb;
    *(ushort4*)&wvb[i * 4] = rc;
    *(ushort4*)&wob[i * 4] = rd;
  } else {
    int t = blockIdx.x - 164;             // 768 blocks: b*96 + (c0/32)*8 + n0/128
    int b = t / 96, rr = t % 96;
    int c0 = (rr >> 3) * 32, n0 = (rr & 7) * 128;
    for (int i = threadIdx.x; i < 4096; i += 256) {
      int n = i >> 5, c = i & 31;
      T[n][c] = f2bf(x[((long)(b * 1024 + n0 + n)) * CDIM + c0 + c]);
    }
    __syncthreads();
    for (int i = threadIdx.x; i < 4096; i += 256) {
      int c = i >> 7, n = i & 127;
      xc[((long)(b * CDIM + c0 + c)) * 1024 + n0 + n] = T[n][c];
    }
  }
}

// ---------------------------------------------------------------------------
// Kernel 1: spectral filter via MFMA + FUSED depthwise conv3x3 + BN.
// TWO channels per block: twiddle tables shared, every barrier-separated
// stage has 2x independent MFMA jobs per wave.
// Tb = tables (0=Tc 1=Ts 2=Tsn 3=Uc 4=Us); Wk[ch]: 0=Xt/Xfr(f32) 1=Xfi(f32)
// 2=R1/Zr 3=I1/Zi 4=Ytr 5=Yti
// ---------------------------------------------------------------------------
__global__ __launch_bounds__(256) void fft_conv_k(
    const ushort* __restrict__ xc, const float* __restrict__ cw,
    const ushort* __restrict__ tbl,
    const float* __restrict__ dwq, const float* __restrict__ dwk, const float* __restrict__ dwv,
    const float* __restrict__ gq, const float* __restrict__ bq, const float* __restrict__ mq, const float* __restrict__ vq,
    const float* __restrict__ gk, const float* __restrict__ bk, const float* __restrict__ mk, const float* __restrict__ vk,
    const float* __restrict__ gv, const float* __restrict__ bv, const float* __restrict__ mv, const float* __restrict__ vv,
    ushort* __restrict__ yc,
    ushort* __restrict__ qc, ushort* __restrict__ kc, ushort* __restrict__ vc)
{
  const int bp = blockIdx.x;
  const int b = bp / 192, cp = (bp % 192) * 2;
  const int tid = threadIdx.x;
  const int w = tid >> 6, lane = tid & 63;
  const int l15 = lane & 15, l16 = lane >> 4;
  __shared__ ushort Tb[5][32][40];
  __shared__ ushort Wk[2][6][32][40];
  __shared__ float Ysf[2][32][33];

  for (int i = tid; i < 640; i += 256) {                 // tables -> LDS
    int t = i >> 7, j = i & 127, r = j >> 2, s = j & 3;
    *(uint4*)&Tb[t][r][s * 8] = *(const uint4*)&tbl[t * 1024 + r * 32 + s * 8];
  }
  for (int i = tid; i < 2048; i += 256) {                // inputs -> Xt[w][h]
    int ch = i >> 10, idx = i & 1023;
    Wk[ch][0][idx & 31][idx >> 5] = xc[(long)(b * CDIM + cp + ch) * 1024 + idx];
  }
  __syncthreads();

  // stage1: R1 = Tc.Xt^T ; I1 = Tsn.Xt^T   (16 jobs: 2ch x 8)
  for (int j = w; j < 16; j += 4) {
    int ch = j >> 3, jj = j & 7;
    int o = jj & 1, ut = (jj >> 1) & 1, wt = (jj >> 2) & 1;
    short8v af = *(const short8v*)&Tb[o == 0 ? 0 : 2][ut * 16 + l15][l16 * 8];
    short8v bf = *(const short8v*)&Wk[ch][0][wt * 16 + l15][l16 * 8];
    float4v acc = {0.f, 0.f, 0.f, 0.f};
    acc = __builtin_amdgcn_mfma_f32_16x16x32_bf16(af, bf, acc, 0, 0, 0);
    int dst = (o == 0) ? 2 : 3;
#pragma unroll
    for (int r = 0; r < 4; ++r)
      Wk[ch][dst][ut * 16 + l16 * 4 + r][wt * 16 + l15] = f2bf(acc[r]);
  }
  __syncthreads();

  // stage2: Xfr = R1.Tc + I1.Ts ; Xfi = I1.Tc + R1.Tsn  (fp32 raw store)
  for (int j = w; j < 16; j += 4) {
    int ch = j >> 3, jj = j & 7;
    int o = jj & 1, ut = (jj >> 1) & 1, vt = (jj >> 2) & 1;
    short8v a1 = *(const short8v*)&Wk[ch][o == 0 ? 2 : 3][ut * 16 + l15][l16 * 8];
    short8v b1 = *(const short8v*)&Tb[0][vt * 16 + l15][l16 * 8];
    short8v a2 = *(const short8v*)&Wk[ch][o == 0 ? 3 : 2][ut * 16 + l15][l16 * 8];
    short8v b2 = *(const short8v*)&Tb[o == 0 ? 1 : 2][vt * 16 + l15][l16 * 8];
    float4v acc = {0.f, 0.f, 0.f, 0.f};
    acc = __builtin_amdgcn_mfma_f32_16x16x32_bf16(a1, b1, acc, 0, 0, 0);
    acc = __builtin_amdgcn_mfma_f32_16x16x32_bf16(a2, b2, acc, 0, 0, 0);
    int v = vt * 16 + l15;
    if (v < 17) {
      float* praw = (float*)&Wk[ch][o == 0 ? 0 : 1][0][0];   // [32][20] f32
#pragma unroll
      for (int r = 0; r < 4; ++r)
        praw[(ut * 16 + l16 * 4 + r) * 20 + v] = acc[r];
    }
  }
  __syncthreads();

  // zero Ytr/Yti rows 17..31, then weight-multiply + transpose scatter
  for (int i = tid; i < 300; i += 256) {
    int ch = i / 150, j2 = i % 150;
    int buf = j2 / 75, j3 = j2 % 75, r2 = 17 + j3 / 5, s2 = j3 % 5;
    uint4 z = {0u, 0u, 0u, 0u};
    *(uint4*)&Wk[ch][4 + buf][r2][s2 * 8] = z;
  }
  for (int e = tid; e < 1088; e += 256) {
    int ch = e >= 544 ? 1 : 0, e2 = e - ch * 544;
    int u = e2 / 17, v = e2 - u * 17;
    const float* xfr = (const float*)&Wk[ch][0][0][0];
    const float* xfi = (const float*)&Wk[ch][1][0][0];
    float fr = xfr[u * 20 + v], fi = xfi[u * 20 + v];
    float2 wc = *(const float2*)&cw[((long)((cp + ch) * 32 + u) * 17 + v) * 2];
    Wk[ch][4][v][u] = f2bf(fr * wc.x - fi * wc.y);
    Wk[ch][5][v][u] = f2bf(fr * wc.y + fi * wc.x);
  }
  __syncthreads();

  // stage3: Zr = Tc(h).Ytr + Tsn(h).Yti ; Zi = Tc(h).Yti + Ts(h).Ytr
  for (int j = w; j < 16; j += 4) {
    int ch = j >> 3, jj = j & 7;
    int o = jj & 1, ht = (jj >> 1) & 1, vt = (jj >> 2) & 1;
    short8v a1 = *(const short8v*)&Tb[0][ht * 16 + l15][l16 * 8];
    short8v b1 = *(const short8v*)&Wk[ch][o == 0 ? 4 : 5][vt * 16 + l15][l16 * 8];
    short8v a2 = *(const short8v*)&Tb[o == 0 ? 2 : 1][ht * 16 + l15][l16 * 8];
    short8v b2 = *(const short8v*)&Wk[ch][o == 0 ? 5 : 4][vt * 16 + l15][l16 * 8];
    float4v acc = {0.f, 0.f, 0.f, 0.f};
    acc = __builtin_amdgcn_mfma_f32_16x16x32_bf16(a1, b1, acc, 0, 0, 0);
    acc = __builtin_amdgcn_mfma_f32_16x16x32_bf16(a2, b2, acc, 0, 0, 0);
    int dst = (o == 0) ? 2 : 3;
#pragma unroll
    for (int r = 0; r < 4; ++r)
      Wk[ch][dst][ht * 16 + l16 * 4 + r][vt * 16 + l15] = f2bf(acc[r]);
  }
  __syncthreads();

  // stage4: y = (Zr.Uc^T + Zi.Us^T)/1024 -> Ysf + yc  (8 jobs: 2ch x 4)
  for (int j = w; j < 8; j += 4) {
    int ch = j >> 2, jj = j & 3;
    int ht = jj & 1, wt = (jj >> 1) & 1;
    short8v a1 = *(const short8v*)&Wk[ch][2][ht * 16 + l15][l16 * 8];
    short8v b1 = *(const short8v*)&Tb[3][wt * 16 + l15][l16 * 8];
    short8v a2 = *(const short8v*)&Wk[ch][3][ht * 16 + l15][l16 * 8];
    short8v b2 = *(const short8v*)&Tb[4][wt * 16 + l15][l16 * 8];
    float4v acc = {0.f, 0.f, 0.f, 0.f};
    acc = __builtin_amdgcn_mfma_f32_16x16x32_bf16(a1, b1, acc, 0, 0, 0);
    acc = __builtin_amdgcn_mfma_f32_16x16x32_bf16(a2, b2, acc, 0, 0, 0);
#pragma unroll
    for (int r = 0; r < 4; ++r) {
      int hh = ht * 16 + l16 * 4 + r, ww = wt * 16 + l15;
      float y = acc[r] * (1.0f / 1024.0f);
      Ysf[ch][hh][ww] = y;
      yc[(long)(b * CDIM + cp + ch) * 1024 + hh * 32 + ww] = f2bf(y);
    }
  }
  __syncthreads();

  // fused depthwise 3x3 conv + BN -> qc/kc/vc
  for (int i = tid; i < 2048; i += 256) {
    int ch = i >> 10, idx = i & 1023;
    int c = cp + ch;
    int hh = idx >> 5, ww = idx & 31;
    float aq = 0.f, ak = 0.f, av = 0.f;
#pragma unroll
    for (int dy = 0; dy < 3; ++dy) {
      int y0 = hh + dy - 1;
#pragma unroll
      for (int dx = 0; dx < 3; ++dx) {
        int x0 = ww + dx - 1;
        float xv = (y0 >= 0 && y0 < 32 && x0 >= 0 && x0 < 32) ? Ysf[ch][y0][x0] : 0.f;
        int t = dy * 3 + dx;
        aq += xv * dwq[c * 9 + t];
        ak += xv * dwk[c * 9 + t];
        av += xv * dwv[c * 9 + t];
      }
    }
    float scq = gq[c] * rsqrtf(vq[c] + 1e-5f);
    float sck = gk[c] * rsqrtf(vk[c] + 1e-5f);
    float scv = gv[c] * rsqrtf(vv[c] + 1e-5f);
    long o = (long)(b * CDIM + c) * 1024 + idx;
    qc[o] = f2bf(aq * scq + (bq[c] - mq[c] * scq));
    kc[o] = f2bf(ak * sck + (bk[c] - mk[c] * sck));
    vc[o] = f2bf(av * scv + (bv[c] - mv[c] * scv));
  }
}

// ---------------------------------------------------------------------------
// MFMA GEMM body  C[m,n'] = sum_k A[m,k] W[n',k]
// tile 128x64, BK=64, 4 waves (2x2), padded LDS (stride 72 bf16 = 144B).
// CMA=true: A is c-major (b,c,n); staging does the n<->c transpose in LDS
//   with a row-XOR column swizzle (col ^ (row&56)).
// flags==0: bf16 store (n-major).  flags==1: fp32 write out = acc+bias+y
// (residual from ycr, c-major bf16).  flags==2: bf16 store c-major (ushort4).
// ---------------------------------------------------------------------------
template<bool CMA>
__device__ __forceinline__ void gemm_body(
    const ushort* __restrict__ A, const ushort* __restrict__ Wb,
    const float* __restrict__ bias, const ushort* __restrict__ ycr,
    void* __restrict__ Cd, int flags, int bx, int by)
{
  __shared__ ushort As[128][72];
  __shared__ ushort Ws[64][72];
  const int tid = threadIdx.x;
  const int w = tid >> 6, lane = tid & 63;
  const int l15 = lane & 15, l16 = lane >> 4;
  const int wm = w >> 1, wn = w & 1;
  const int row0 = bx * 128, col0 = by * 64;
  const int btok = row0 >> 10;           // batch index
  const int ntok0 = row0 & 1023;
  float4v acc[4][2];
#pragma unroll
  for (int i = 0; i < 4; ++i)
#pragma unroll
    for (int j = 0; j < 2; ++j) acc[i][j] = (float4v){0.f, 0.f, 0.f, 0.f};
  for (int kt = 0; kt < CDIM; kt += 64) {
    if (kt) __syncthreads();
    if (CMA) {
      const int g = tid & 15, u = tid >> 4;
      const int c0 = u * 4;
      const long abase = ((long)(btok * CDIM + kt + c0)) * 1024 + ntok0 + g * 8;
      uint4 t0 = *(const uint4*)&A[abase + 0 * 1024];
      uint4 t1 = *(const uint4*)&A[abase + 1 * 1024];
      uint4 t2 = *(const uint4*)&A[abase + 2 * 1024];
      uint4 t3 = *(const uint4*)&A[abase + 3 * 1024];
      const ushort* s0 = (const ushort*)&t0;
      const ushort* s1 = (const ushort*)&t1;
      const ushort* s2 = (const ushort*)&t2;
      const ushort* s3 = (const ushort*)&t3;
      const int colu = c0 ^ ((g & 7) << 3);
#pragma unroll
      for (int i = 0; i < 8; ++i) {
        uint2 wv;
        wv.x = (unsigned)s0[i] | ((unsigned)s1[i] << 16);
        wv.y = (unsigned)s2[i] | ((unsigned)s3[i] << 16);
        *(uint2*)&As[g * 8 + i][colu] = wv;
      }
    } else {
      for (int c = tid; c < 1024; c += 256) {
        int r = c >> 3, s = c & 7;
        *(uint4*)&As[r][s * 8] = *(const uint4*)&A[(long)(row0 + r) * CDIM + kt + s * 8];
      }
    }
    for (int c = tid; c < 512; c += 256) {
      int r = c >> 3, s = c & 7;
      *(uint4*)&Ws[r][s * 8] = *(const uint4*)&Wb[(long)(col0 + r) * CDIM + kt + s * 8];
    }
    __syncthreads();
#pragma unroll
    for (int s = 0; s < 2; ++s) {
      short8v a[4], bfr[2];
#pragma unroll
      for (int i = 0; i < 4; ++i) {
        int arow = wm * 64 + i * 16 + l15;
        int acol = s * 32 + l16 * 8;
        if (CMA) acol ^= (arow & 56);
        a[i] = *(const short8v*)&As[arow][acol];
      }
#pragma unroll
      for (int j = 0; j < 2; ++j)
        bfr[j] = *(const short8v*)&Ws[wn * 32 + j * 16 + l15][s * 32 + l16 * 8];
#pragma unroll
      for (int i = 0; i < 4; ++i)
#pragma unroll
        for (int j = 0; j < 2; ++j)
          acc[i][j] = __builtin_amdgcn_mfma_f32_16x16x32_bf16(a[i], bfr[j], acc[i][j], 0, 0, 0);
    }
  }
#pragma unroll
  for (int i = 0; i < 4; ++i)
#pragma unroll
    for (int j = 0; j < 2; ++j) {
      int col = col0 + wn * 32 + j * 16 + l15;
      int rbase = row0 + wm * 64 + i * 16 + l16 * 4;
      int ntok = ntok0 + wm * 64 + i * 16 + l16 * 4;
      if (flags == 2) {
        ushort4 pk = { f2bf(acc[i][j][0]), f2bf(acc[i][j][1]),
                       f2bf(acc[i][j][2]), f2bf(acc[i][j][3]) };
        *(ushort4*)&((ushort*)Cd)[((long)(btok * CDIM + col)) * 1024 + ntok] = pk;
      } else if (flags == 1) {
        ushort4 yv = *(const ushort4*)&ycr[((long)(btok * CDIM + col)) * 1024 + ntok];
        float bcol = bias[col];
        float* op = (float*)Cd;
        op[(long)(rbase + 0) * CDIM + col] = acc[i][j][0] + bcol + bf2f(yv.x);
        op[(long)(rbase + 1) * CDIM + col] = acc[i][j][1] + bcol + bf2f(yv.y);
        op[(long)(rbase + 2) * CDIM + col] = acc[i][j][2] + bcol + bf2f(yv.z);
        op[(long)(rbase + 3) * CDIM + col] = acc[i][j][3] + bcol + bf2f(yv.w);
      } else {
#pragma unroll
        for (int r = 0; r < 4; ++r)
          ((ushort*)Cd)[(long)(rbase + r) * CDIM + col] = f2bf(acc[i][j][r]);
      }
    }
}

// fused q/k/v projection GEMMs reading c-major conv outputs directly.
// z==2 (V) writes its output c-major.
__global__ __launch_bounds__(256) void gemm_qkv_k(
    const ushort* __restrict__ qc, const ushort* __restrict__ kc, const ushort* __restrict__ vc,
    const ushort* __restrict__ wqb, const ushort* __restrict__ wkb, const ushort* __restrict__ wvb,
    ushort* __restrict__ q1, ushort* __restrict__ k1, ushort* __restrict__ vtc)
{
  const int z = blockIdx.z;
  const ushort* A  = z == 0 ? qc  : z == 1 ? kc  : vc;
  const ushort* Wb = z == 0 ? wqb : z == 1 ? wkb : wvb;
  ushort*       C  = z == 0 ? q1  : z == 1 ? k1  : vtc;
  gemm_body<true>(A, Wb, nullptr, nullptr, C, z == 2 ? 2 : 0, blockIdx.x, blockIdx.y);
}

// final projection: out = A@wo^T + bo + x_fft (residual from yc)
__global__ __launch_bounds__(256) void gemm_out_k(
    const ushort* __restrict__ A, const ushort* __restrict__ Wb,
    const float* __restrict__ bias, const ushort* __restrict__ ycr,
    float* __restrict__ Cd)
{
  gemm_body<false>(A, Wb, bias, ycr, Cd, 1, blockIdx.x, blockIdx.y);
}

// ---------------------------------------------------------------------------
// Kernel 4: MFMA flash attention, TWO 64-row q-tiles per block (grid 64x8).
// K/V staging + barriers shared by 2x compute.  Swapped QK^T, cvt_pk P pack,
// no-max softmax, ones-MFMA row sums, Q direct from global, T14-lite reg
// prefetch of the next K/V tile.
// ---------------------------------------------------------------------------
__global__ __launch_bounds__(256) void attn_mfma_k(
    const ushort* __restrict__ q1, const ushort* __restrict__ k1,
    const ushort* __restrict__ vt, ushort* __restrict__ ao)
{
  const int bh = blockIdx.x, qt2 = blockIdx.y;
  const int b = bh >> 3, h = bh & 7;
  const int tid = threadIdx.x;
  const int w = tid >> 6, lane = tid & 63;
  const int l15 = lane & 15, l16 = lane >> 4;
  __shared__ ushort Ks[64][72], Vs[48][72], Ps[128][72];
  const float scale = 0.051031036307982884f;  // 384^-0.5
  const long base = (long)b * NPIX * CDIM + h * 48;
  const long vbase = (long)bh * 48 * NPIX;

  // per-thread staging descriptors (scalars -> no scratch).
  const int i0 = tid, i1 = tid + 256, i2 = tid + 512;
  const int r0 = i0 / 6, s0 = i0 - r0 * 6;
  const ushort* gp0 = k1 + base + (long)r0 * CDIM + s0 * 8;
  const long st0 = (long)64 * CDIM;
  ushort* lp0 = &Ks[r0][s0 * 8];
  const ushort* gp1; long st1; ushort* lp1;
  if (i1 < 384) {
    int r = i1 / 6, s = i1 - r * 6;
    gp1 = k1 + base + (long)r * CDIM + s * 8; st1 = (long)64 * CDIM; lp1 = &Ks[r][s * 8];
  } else {
    int j = i1 - 384, d = j >> 3, s = j & 7;
    gp1 = vt + vbase + (long)d * NPIX + s * 8; st1 = 64; lp1 = &Vs[d][s * 8];
  }
  const int j2 = i2 - 384, d2 = j2 >> 3, s2 = j2 & 7;
  const ushort* gp2 = vt + vbase + (long)d2 * NPIX + s2 * 8;
  const long st2 = 64;
  ushort* lp2 = &Vs[d2][s2 * 8];

  // zero K pad (cols 48..63), persists across iterations
  if (tid < 128) {
    uint4 z4 = {0u, 0u, 0u, 0u};
    int r = tid >> 1, s = tid & 1;
    *(uint4*)&Ks[r][48 + s * 8] = z4;
  }
  // Q fragments for both q-tile halves, direct from global
  const long qrowA = base + (long)(qt2 * 128 + w * 16 + l15) * CDIM;
  const long qrowB = qrowA + (long)64 * CDIM;
  short8v qa0A = *(const short8v*)&q1[qrowA + l16 * 8];
  short8v qa0B = *(const short8v*)&q1[qrowB + l16 * 8];
  short8v qa1A, qa1B;
  {
    short8v qz = {};
    short8v qvA = *(const short8v*)&q1[qrowA + ((l16 < 2) ? 32 + l16 * 8 : 0)];
    short8v qvB = *(const short8v*)&q1[qrowB + ((l16 < 2) ? 32 + l16 * 8 : 0)];
    qa1A = (l16 < 2) ? qvA : qz;
    qa1B = (l16 < 2) ? qvB : qz;
  }

  float lrunA[4] = {0.f, 0.f, 0.f, 0.f}, lrunB[4] = {0.f, 0.f, 0.f, 0.f};
  float4v accOA[3], accOB[3];
#pragma unroll
  for (int fd = 0; fd < 3; ++fd) {
    accOA[fd] = (float4v){0.f, 0.f, 0.f, 0.f};
    accOB[fd] = (float4v){0.f, 0.f, 0.f, 0.f};
  }
  short8v onesb;
#pragma unroll
  for (int j = 0; j < 8; ++j) onesb[j] = (short)0x3F80;  // bf16 1.0

  uint4 t0 = *(const uint4*)gp0;          // tile 0 loads
  uint4 t1 = *(const uint4*)gp1;
  uint4 t2 = *(const uint4*)gp2;

  for (int kt = 0; kt < 16; ++kt) {
    *(uint4*)lp0 = t0;
    *(uint4*)lp1 = t1;
    *(uint4*)lp2 = t2;
    __syncthreads();
    if (kt + 1 < 16) {                    // issue loads for t+1 under compute
      t0 = *(const uint4*)(gp0 + (long)(kt + 1) * st0);
      t1 = *(const uint4*)(gp1 + (long)(kt + 1) * st1);
      t2 = *(const uint4*)(gp2 + (long)(kt + 1) * st2);
    }
    // swapped QK^T for both halves: K frags loaded once
    float4v saccA[4], saccB[4];
#pragma unroll
    for (int fc = 0; fc < 4; ++fc) {
      short8v kb0 = *(const short8v*)&Ks[fc * 16 + l15][l16 * 8];
      short8v kb1 = *(const short8v*)&Ks[fc * 16 + l15][32 + l16 * 8];
      saccA[fc] = (float4v){0.f, 0.f, 0.f, 0.f};
      saccA[fc] = __builtin_amdgcn_mfma_f32_16x16x32_bf16(kb0, qa0A, saccA[fc], 0, 0, 0);
      saccA[fc] = __builtin_amdgcn_mfma_f32_16x16x32_bf16(kb1, qa1A, saccA[fc], 0, 0, 0);
      saccB[fc] = (float4v){0.f, 0.f, 0.f, 0.f};
      saccB[fc] = __builtin_amdgcn_mfma_f32_16x16x32_bf16(kb0, qa0B, saccB[fc], 0, 0, 0);
      saccB[fc] = __builtin_amdgcn_mfma_f32_16x16x32_bf16(kb1, qa1B, saccB[fc], 0, 0, 0);
    }
    // P = exp(S*scale); pack pairs -> dword stores (rows wave-private)
    unsigned* prowA = (unsigned*)&Ps[w * 16 + l15][0];
    unsigned* prowB = (unsigned*)&Ps[64 + w * 16 + l15][0];
#pragma unroll
    for (int fc = 0; fc < 4; ++fc) {
      float a0 = __expf(saccA[fc][0] * scale), a1 = __expf(saccA[fc][1] * scale);
      float a2 = __expf(saccA[fc][2] * scale), a3 = __expf(saccA[fc][3] * scale);
      __hip_bfloat162 dA01 = __float22bfloat162_rn(make_float2(a0, a1));
      __hip_bfloat162 dA23 = __float22bfloat162_rn(make_float2(a2, a3));
      prowA[fc * 8 + l16 * 2 + 0] = *(unsigned*)&dA01;
      prowA[fc * 8 + l16 * 2 + 1] = *(unsigned*)&dA23;
      float b0 = __expf(saccB[fc][0] * scale), b1 = __expf(saccB[fc][1] * scale);
      float b2 = __expf(saccB[fc][2] * scale), b3 = __expf(saccB[fc][3] * scale);
      __hip_bfloat162 dB01 = __float22bfloat162_rn(make_float2(b0, b1));
      __hip_bfloat162 dB23 = __float22bfloat162_rn(make_float2(b2, b3));
      prowB[fc * 8 + l16 * 2 + 0] = *(unsigned*)&dB01;
      prowB[fc * 8 + l16 * 2 + 1] = *(unsigned*)&dB23;
    }
    asm volatile("s_waitcnt lgkmcnt(0)" ::: "memory");
    __builtin_amdgcn_sched_barrier(0);
    short8v pa0A = *(const short8v*)&Ps[w * 16 + l15][l16 * 8];
    short8v pa1A = *(const short8v*)&Ps[w * 16 + l15][32 + l16 * 8];
    short8v pa0B = *(const short8v*)&Ps[64 + w * 16 + l15][l16 * 8];
    short8v pa1B = *(const short8v*)&Ps[64 + w * 16 + l15][32 + l16 * 8];
    // row sums via ones-MFMA
    float4v srA = (float4v){0.f, 0.f, 0.f, 0.f};
    srA = __builtin_amdgcn_mfma_f32_16x16x32_bf16(pa0A, onesb, srA, 0, 0, 0);
    srA = __builtin_amdgcn_mfma_f32_16x16x32_bf16(pa1A, onesb, srA, 0, 0, 0);
    float4v srB = (float4v){0.f, 0.f, 0.f, 0.f};
    srB = __builtin_amdgcn_mfma_f32_16x16x32_bf16(pa0B, onesb, srB, 0, 0, 0);
    srB = __builtin_amdgcn_mfma_f32_16x16x32_bf16(pa1B, onesb, srB, 0, 0, 0);
#pragma unroll
    for (int r = 0; r < 4; ++r) { lrunA[r] += srA[r]; lrunB[r] += srB[r]; }
    // PV for both halves; V frags loaded once
#pragma unroll
    for (int fd = 0; fd < 3; ++fd) {
      short8v vb0 = *(const short8v*)&Vs[fd * 16 + l15][l16 * 8];
      short8v vb1 = *(const short8v*)&Vs[fd * 16 + l15][32 + l16 * 8];
      accOA[fd] = __builtin_amdgcn_mfma_f32_16x16x32_bf16(pa0A, vb0, accOA[fd], 0, 0, 0);
      accOA[fd] = __builtin_amdgcn_mfma_f32_16x16x32_bf16(pa1A, vb1, accOA[fd], 0, 0, 0);
      accOB[fd] = __builtin_amdgcn_mfma_f32_16x16x32_bf16(pa0B, vb0, accOB[fd], 0, 0, 0);
      accOB[fd] = __builtin_amdgcn_mfma_f32_16x16x32_bf16(pa1B, vb1, accOB[fd], 0, 0, 0);
    }
    __syncthreads();                      // compute done; LDS free for t+1
  }
  float invA[4], invB[4];
#pragma unroll
  for (int r = 0; r < 4; ++r) { invA[r] = 1.f / lrunA[r]; invB[r] = 1.f / lrunB[r]; }
#pragma unroll
  for (int fd = 0; fd < 3; ++fd)
#pragma unroll
    for (int r = 0; r < 4; ++r) {
      int qrA = qt2 * 128 + w * 16 + l16 * 4 + r;
      ao[base + (long)qrA * CDIM + fd * 16 + l15] = f2bf(accOA[fd][r] * invA[r]);
      ao[base + (long)(qrA + 64) * CDIM + fd * 16 + l15] = f2bf(accOB[fd][r] * invB[r]);
    }
}

// ---------------------------------------------------------------------------
extern "C" void kernel_launch(void* const* d_in, const int* in_sizes, int n_in,
                              void* d_out, int out_size, void* d_ws, size_t ws_size,
                              hipStream_t stream) {
  const float* x   = (const float*)d_in[0];
  const float* cw  = (const float*)d_in[1];
  const float* dwq = (const float*)d_in[2];
  const float* dwk = (const float*)d_in[3];
  const float* dwv = (const float*)d_in[4];
  const float* gq  = (const float*)d_in[5];
  const float* bq  = (const float*)d_in[6];
  const float* mq  = (const float*)d_in[7];
  const float* vq  = (const float*)d_in[8];
  const float* gk  = (const float*)d_in[9];
  const float* bk  = (const float*)d_in[10];
  const float* mk  = (const float*)d_in[11];
  const float* vk  = (const float*)d_in[12];
  const float* gv  = (const float*)d_in[13];
  const float* bv  = (const float*)d_in[14];
  const float* mv  = (const float*)d_in[15];
  const float* vv  = (const float*)d_in[16];
  const float* wq  = (const float*)d_in[17];
  const float* wk  = (const float*)d_in[18];
  const float* wv  = (const float*)d_in[19];
  const float* wo  = (const float*)d_in[20];
  const float* bo  = (const float*)d_in[21];
  float* out = (float*)d_out;

  char* wsb = (char*)d_ws;
  const size_t H = (size_t)NB * NPIX * CDIM * 2;        // 6,291,456 B
  // slot plan (each H):
  // S0: xc -> vtc | S1: yc | S2: qc -> ao | S3: kc | S4: vc
  // S5: q1 | S6: k1 | S7: weights + tbl
  ushort* xcp = (ushort*)(wsb + 0 * H);
  ushort* vtc = (ushort*)(wsb + 0 * H);
  ushort* yc  = (ushort*)(wsb + 1 * H);
  ushort* qc  = (ushort*)(wsb + 2 * H);
  ushort* ao  = (ushort*)(wsb + 2 * H);
  ushort* kc  = (ushort*)(wsb + 3 * H);
  ushort* vc  = (ushort*)(wsb + 4 * H);
  ushort* q1  = (ushort*)(wsb + 5 * H);
  ushort* k1  = (ushort*)(wsb + 6 * H);
  ushort* wqb = (ushort*)(wsb + 7 * H);
  ushort* wkb = wqb + CDIM * CDIM;
  ushort* wvb = wkb + CDIM * CDIM;
  ushort* wob = wvb + CDIM * CDIM;
  ushort* tbl = wob + CDIM * CDIM;                      // 5*1024 ushorts

  prep_k<<<dim3(932), 256, 0, stream>>>(tbl, wq, wk, wv, wo,
      wqb, wkb, wvb, wob, x, xcp);
  fft_conv_k<<<dim3(NB * CDIM / 2), 256, 0, stream>>>(xcp, cw, tbl, dwq, dwk, dwv,
      gq, bq, mq, vq, gk, bk, mk, vk, gv, bv, mv, vv, yc, qc, kc, vc);
  gemm_qkv_k<<<dim3(64, 6, 3), 256, 0, stream>>>(qc, kc, vc, wqb, wkb, wvb, q1, k1, vtc);
  attn_mfma_k<<<dim3(64, 8), 256, 0, stream>>>(q1, k1, vtc, ao);
  gemm_out_k<<<dim3(64, 6), 256, 0, stream>>>(ao, wob, bo, yc, out);
}

// Round 15
// 102.448 us; speedup vs baseline: 1.0953x; 1.0953x over previous
//
#include <hip/hip_runtime.h>
#include <hip/hip_bf16.h>
#include <cmath>

#define CDIM 384
#define NB 8
#define NPIX 1024

typedef __attribute__((ext_vector_type(8))) short short8v;
typedef __attribute__((ext_vector_type(4))) float float4v;

__device__ __forceinline__ ushort f2bf(float f) {
  union { float f; unsigned u; } v; v.f = f;
  unsigned r = (v.u + 0x7fffu + ((v.u >> 16) & 1u)) >> 16;
  return (ushort)r;
}
__device__ __forceinline__ float bf2f(ushort u) {
  union { unsigned u; float f; } v; v.u = ((unsigned)u) << 16;
  return v.f;
}

// ---------------------------------------------------------------------------
// Kernel 0 (merged): blocks 0..19 bf16 twiddle tables; 20..163 projection
// weights -> bf16; 164..931 x (b,n,c) f32 -> xc (b,c,n) bf16 transpose.
// ---------------------------------------------------------------------------
__global__ __launch_bounds__(256) void prep_k(
    ushort* __restrict__ tbl,
    const float* __restrict__ wq, const float* __restrict__ wk,
    const float* __restrict__ wv, const float* __restrict__ wo,
    ushort* __restrict__ wqb, ushort* __restrict__ wkb,
    ushort* __restrict__ wvb, ushort* __restrict__ wob,
    const float* __restrict__ x, ushort* __restrict__ xc)
{
  __shared__ ushort T[128][33];
  if (blockIdx.x < 20) {
    int i = blockIdx.x * 256 + threadIdx.x;
    if (i >= 5 * 1024) return;
    int t = i >> 10, j = i & 1023, r = j >> 5, cidx = j & 31;
    float ang = (float)((r * cidx) & 31) * 0.19634954084936207f;
    float val;
    if (t == 0) val = cosf(ang);
    else if (t == 1) val = sinf(ang);
    else if (t == 2) val = -sinf(ang);
    else {
      if (cidx > 16) val = 0.f;
      else {
        float cv = (cidx == 0 || cidx == 16) ? 1.f : 2.f;
        val = (t == 3) ? cv * cosf(ang) : -cv * sinf(ang);
      }
    }
    tbl[i] = f2bf(val);
  } else if (blockIdx.x < 164) {
    int i = (blockIdx.x - 20) * 256 + threadIdx.x;
    if (i * 4 >= CDIM * CDIM) return;
    float4 va = *(const float4*)&wq[i * 4];
    float4 vb = *(const float4*)&wk[i * 4];
    float4 vc = *(const float4*)&wv[i * 4];
    float4 vd = *(const float4*)&wo[i * 4];
    ushort4 ra = { f2bf(va.x), f2bf(va.y), f2bf(va.z), f2bf(va.w) };
    ushort4 rb = { f2bf(vb.x), f2bf(vb.y), f2bf(vb.z), f2bf(vb.w) };
    ushort4 rc = { f2bf(vc.x), f2bf(vc.y), f2bf(vc.z), f2bf(vc.w) };
    ushort4 rd = { f2bf(vd.x), f2bf(vd.y), f2bf(vd.z), f2bf(vd.w) };
    *(ushort4*)&wqb[i * 4] = ra;
    *(ushort4*)&wkb[i * 4] = rb;
    *(ushort4*)&wvb[i * 4] = rc;
    *(ushort4*)&wob[i * 4] = rd;
  } else {
    int t = blockIdx.x - 164;             // 768 blocks: b*96 + (c0/32)*8 + n0/128
    int b = t / 96, rr = t % 96;
    int c0 = (rr >> 3) * 32, n0 = (rr & 7) * 128;
    for (int i = threadIdx.x; i < 4096; i += 256) {
      int n = i >> 5, c = i & 31;
      T[n][c] = f2bf(x[((long)(b * 1024 + n0 + n)) * CDIM + c0 + c]);
    }
    __syncthreads();
    for (int i = threadIdx.x; i < 4096; i += 256) {
      int c = i >> 7, n = i & 127;
      xc[((long)(b * CDIM + c0 + c)) * 1024 + n0 + n] = T[n][c];
    }
  }
}

// ---------------------------------------------------------------------------
// Kernel 1: spectral filter via MFMA + FUSED depthwise conv3x3 + BN.
// ONE channel per block (round-13 structure: 32KB LDS, 5 blocks/CU).
// ---------------------------------------------------------------------------
__global__ __launch_bounds__(256) void fft_conv_k(
    const ushort* __restrict__ xc, const float* __restrict__ cw,
    const ushort* __restrict__ tbl,
    const float* __restrict__ dwq, const float* __restrict__ dwk, const float* __restrict__ dwv,
    const float* __restrict__ gq, const float* __restrict__ bq, const float* __restrict__ mq, const float* __restrict__ vq,
    const float* __restrict__ gk, const float* __restrict__ bk, const float* __restrict__ mk, const float* __restrict__ vk,
    const float* __restrict__ gv, const float* __restrict__ bv, const float* __restrict__ mv, const float* __restrict__ vv,
    ushort* __restrict__ yc,
    ushort* __restrict__ qc, ushort* __restrict__ kc, ushort* __restrict__ vc)
{
  const int b = blockIdx.x / CDIM, c = blockIdx.x % CDIM;
  const int tid = threadIdx.x;
  const int w = tid >> 6, lane = tid & 63;
  const int l15 = lane & 15, l16 = lane >> 4;
  __shared__ ushort B[11][32][40];
  __shared__ float Ysf[32][33];

  float wq9[9], wk9[9], wv9[9];
#pragma unroll
  for (int t = 0; t < 9; ++t) {
    wq9[t] = dwq[c * 9 + t];
    wk9[t] = dwk[c * 9 + t];
    wv9[t] = dwv[c * 9 + t];
  }
  float scq = gq[c] * rsqrtf(vq[c] + 1e-5f); float shq = bq[c] - mq[c] * scq;
  float sck = gk[c] * rsqrtf(vk[c] + 1e-5f); float shk = bk[c] - mk[c] * sck;
  float scv = gv[c] * rsqrtf(vv[c] + 1e-5f); float shv = bv[c] - mv[c] * scv;

  for (int i = tid; i < 640; i += 256) {                 // tables -> LDS
    int t = i >> 7, j = i & 127, r = j >> 2, s = j & 3;
    *(uint4*)&B[t][r][s * 8] = *(const uint4*)&tbl[t * 1024 + r * 32 + s * 8];
  }
  for (int i = tid; i < 1024; i += 256)                  // input -> Xt[w][h]
    B[5][i & 31][i >> 5] = xc[(long)(b * CDIM + c) * 1024 + i];
  __syncthreads();

  // stage1: R1[u,w] = sum_h Tc[u,h]*Xt[w,h];  I1 = sum_h Tsn[u,h]*Xt[w,h]
  for (int j = w; j < 8; j += 4) {
    int o = j & 1, ut = (j >> 1) & 1, wt = (j >> 2) & 1;
    short8v af = *(const short8v*)&B[o == 0 ? 0 : 2][ut * 16 + l15][l16 * 8];
    short8v bf = *(const short8v*)&B[5][wt * 16 + l15][l16 * 8];
    float4v acc = {0.f, 0.f, 0.f, 0.f};
    acc = __builtin_amdgcn_mfma_f32_16x16x32_bf16(af, bf, acc, 0, 0, 0);
    int dst = (o == 0) ? 7 : 8;
#pragma unroll
    for (int r = 0; r < 4; ++r)
      B[dst][ut * 16 + l16 * 4 + r][wt * 16 + l15] = f2bf(acc[r]);
  }
  __syncthreads();

  // stage2: Xfr[u,v] = R1.Tc + I1.Ts ; Xfi = I1.Tc + R1.Tsn  (fp32 raw store)
  for (int j = w; j < 8; j += 4) {
    int o = j & 1, ut = (j >> 1) & 1, vt = (j >> 2) & 1;
    short8v a1 = *(const short8v*)&B[o == 0 ? 7 : 8][ut * 16 + l15][l16 * 8];
    short8v b1 = *(const short8v*)&B[0][vt * 16 + l15][l16 * 8];
    short8v a2 = *(const short8v*)&B[o == 0 ? 8 : 7][ut * 16 + l15][l16 * 8];
    short8v b2 = *(const short8v*)&B[o == 0 ? 1 : 2][vt * 16 + l15][l16 * 8];
    float4v acc = {0.f, 0.f, 0.f, 0.f};
    acc = __builtin_amdgcn_mfma_f32_16x16x32_bf16(a1, b1, acc, 0, 0, 0);
    acc = __builtin_amdgcn_mfma_f32_16x16x32_bf16(a2, b2, acc, 0, 0, 0);
    int v = vt * 16 + l15;
    if (v < 17) {
      float* praw = (float*)&B[o == 0 ? 5 : 6][0][0];    // [32][20] f32 view
#pragma unroll
      for (int r = 0; r < 4; ++r)
        praw[(ut * 16 + l16 * 4 + r) * 20 + v] = acc[r];
    }
  }
  __syncthreads();

  // zero Ytr/Yti rows 17..31, then weight-multiply + transpose scatter
  for (int i = tid; i < 150; i += 256) {
    int buf = i / 75, j2 = i % 75, r2 = 17 + j2 / 5, s2 = j2 % 5;
    uint4 z = {0u, 0u, 0u, 0u};
    *(uint4*)&B[9 + buf][r2][s2 * 8] = z;
  }
  {
    const float* xfr = (const float*)&B[5][0][0];
    const float* xfi = (const float*)&B[6][0][0];
    for (int e = tid; e < 544; e += 256) {
      int u = e / 17, v = e - u * 17;
      float fr = xfr[u * 20 + v], fi = xfi[u * 20 + v];
      float2 wc = *(const float2*)&cw[((long)(c * 32 + u) * 17 + v) * 2];
      B[9][v][u]  = f2bf(fr * wc.x - fi * wc.y);
      B[10][v][u] = f2bf(fr * wc.y + fi * wc.x);
    }
  }
  __syncthreads();

  // stage3: Zr[h,v] = Tc(h).Ytr + Tsn(h).Yti ; Zi = Tc(h).Yti + Ts(h).Ytr
  for (int j = w; j < 8; j += 4) {
    int o = j & 1, ht = (j >> 1) & 1, vt = (j >> 2) & 1;
    short8v a1 = *(const short8v*)&B[0][ht * 16 + l15][l16 * 8];
    short8v b1 = *(const short8v*)&B[o == 0 ? 9 : 10][vt * 16 + l15][l16 * 8];
    short8v a2 = *(const short8v*)&B[o == 0 ? 2 : 1][ht * 16 + l15][l16 * 8];
    short8v b2 = *(const short8v*)&B[o == 0 ? 10 : 9][vt * 16 + l15][l16 * 8];
    float4v acc = {0.f, 0.f, 0.f, 0.f};
    acc = __builtin_amdgcn_mfma_f32_16x16x32_bf16(a1, b1, acc, 0, 0, 0);
    acc = __builtin_amdgcn_mfma_f32_16x16x32_bf16(a2, b2, acc, 0, 0, 0);
    int dst = (o == 0) ? 7 : 8;
#pragma unroll
    for (int r = 0; r < 4; ++r)
      B[dst][ht * 16 + l16 * 4 + r][vt * 16 + l15] = f2bf(acc[r]);
  }
  __syncthreads();

  // stage4: y[h,w] = (Zr.Uc^T + Zi.Us^T)/1024 -> Ysf (LDS) + yc (coalesced)
  {
    int ht = w & 1, wt = (w >> 1) & 1;
    short8v a1 = *(const short8v*)&B[7][ht * 16 + l15][l16 * 8];
    short8v b1 = *(const short8v*)&B[3][wt * 16 + l15][l16 * 8];
    short8v a2 = *(const short8v*)&B[8][ht * 16 + l15][l16 * 8];
    short8v b2 = *(const short8v*)&B[4][wt * 16 + l15][l16 * 8];
    float4v acc = {0.f, 0.f, 0.f, 0.f};
    acc = __builtin_amdgcn_mfma_f32_16x16x32_bf16(a1, b1, acc, 0, 0, 0);
    acc = __builtin_amdgcn_mfma_f32_16x16x32_bf16(a2, b2, acc, 0, 0, 0);
#pragma unroll
    for (int r = 0; r < 4; ++r) {
      int hh = ht * 16 + l16 * 4 + r, ww = wt * 16 + l15;
      float y = acc[r] * (1.0f / 1024.0f);
      Ysf[hh][ww] = y;
      yc[(long)(b * CDIM + c) * 1024 + hh * 32 + ww] = f2bf(y);
    }
  }
  __syncthreads();

  // fused depthwise 3x3 conv + BN -> qc/kc/vc (bf16, b,c,n — coalesced)
  for (int i = tid; i < 1024; i += 256) {
    int hh = i >> 5, ww = i & 31;
    float aq = 0.f, ak = 0.f, av = 0.f;
#pragma unroll
    for (int dy = 0; dy < 3; ++dy) {
      int y0 = hh + dy - 1;
#pragma unroll
      for (int dx = 0; dx < 3; ++dx) {
        int x0 = ww + dx - 1;
        float xv = (y0 >= 0 && y0 < 32 && x0 >= 0 && x0 < 32) ? Ysf[y0][x0] : 0.f;
        int t = dy * 3 + dx;
        aq += xv * wq9[t]; ak += xv * wk9[t]; av += xv * wv9[t];
      }
    }
    long o = (long)(b * CDIM + c) * 1024 + i;
    qc[o] = f2bf(aq * scq + shq);
    kc[o] = f2bf(ak * sck + shk);
    vc[o] = f2bf(av * scv + shv);
  }
}

// ---------------------------------------------------------------------------
// MFMA GEMM body  C[m,n'] = sum_k A[m,k] W[n',k]
// tile 128x64, BK=64, 4 waves (2x2), padded LDS (stride 72 bf16 = 144B).
// CMA=true: A is c-major (b,c,n); staging does the n<->c transpose in LDS
//   with a row-XOR column swizzle (col ^ (row&56)).
// flags==0: bf16 store (n-major).  flags==1: fp32 write out = acc+bias+y
// (residual from ycr, c-major bf16).  flags==2: bf16 store c-major (ushort4).
// ---------------------------------------------------------------------------
template<bool CMA>
__device__ __forceinline__ void gemm_body(
    const ushort* __restrict__ A, const ushort* __restrict__ Wb,
    const float* __restrict__ bias, const ushort* __restrict__ ycr,
    void* __restrict__ Cd, int flags, int bx, int by)
{
  __shared__ ushort As[128][72];
  __shared__ ushort Ws[64][72];
  const int tid = threadIdx.x;
  const int w = tid >> 6, lane = tid & 63;
  const int l15 = lane & 15, l16 = lane >> 4;
  const int wm = w >> 1, wn = w & 1;
  const int row0 = bx * 128, col0 = by * 64;
  const int btok = row0 >> 10;           // batch index
  const int ntok0 = row0 & 1023;
  float4v acc[4][2];
#pragma unroll
  for (int i = 0; i < 4; ++i)
#pragma unroll
    for (int j = 0; j < 2; ++j) acc[i][j] = (float4v){0.f, 0.f, 0.f, 0.f};
  for (int kt = 0; kt < CDIM; kt += 64) {
    if (kt) __syncthreads();
    if (CMA) {
      const int g = tid & 15, u = tid >> 4;
      const int c0 = u * 4;
      const long abase = ((long)(btok * CDIM + kt + c0)) * 1024 + ntok0 + g * 8;
      uint4 t0 = *(const uint4*)&A[abase + 0 * 1024];
      uint4 t1 = *(const uint4*)&A[abase + 1 * 1024];
      uint4 t2 = *(const uint4*)&A[abase + 2 * 1024];
      uint4 t3 = *(const uint4*)&A[abase + 3 * 1024];
      const ushort* s0 = (const ushort*)&t0;
      const ushort* s1 = (const ushort*)&t1;
      const ushort* s2 = (const ushort*)&t2;
      const ushort* s3 = (const ushort*)&t3;
      const int colu = c0 ^ ((g & 7) << 3);
#pragma unroll
      for (int i = 0; i < 8; ++i) {
        uint2 wv;
        wv.x = (unsigned)s0[i] | ((unsigned)s1[i] << 16);
        wv.y = (unsigned)s2[i] | ((unsigned)s3[i] << 16);
        *(uint2*)&As[g * 8 + i][colu] = wv;
      }
    } else {
      for (int c = tid; c < 1024; c += 256) {
        int r = c >> 3, s = c & 7;
        *(uint4*)&As[r][s * 8] = *(const uint4*)&A[(long)(row0 + r) * CDIM + kt + s * 8];
      }
    }
    for (int c = tid; c < 512; c += 256) {
      int r = c >> 3, s = c & 7;
      *(uint4*)&Ws[r][s * 8] = *(const uint4*)&Wb[(long)(col0 + r) * CDIM + kt + s * 8];
    }
    __syncthreads();
#pragma unroll
    for (int s = 0; s < 2; ++s) {
      short8v a[4], bfr[2];
#pragma unroll
      for (int i = 0; i < 4; ++i) {
        int arow = wm * 64 + i * 16 + l15;
        int acol = s * 32 + l16 * 8;
        if (CMA) acol ^= (arow & 56);
        a[i] = *(const short8v*)&As[arow][acol];
      }
#pragma unroll
      for (int j = 0; j < 2; ++j)
        bfr[j] = *(const short8v*)&Ws[wn * 32 + j * 16 + l15][s * 32 + l16 * 8];
#pragma unroll
      for (int i = 0; i < 4; ++i)
#pragma unroll
        for (int j = 0; j < 2; ++j)
          acc[i][j] = __builtin_amdgcn_mfma_f32_16x16x32_bf16(a[i], bfr[j], acc[i][j], 0, 0, 0);
    }
  }
#pragma unroll
  for (int i = 0; i < 4; ++i)
#pragma unroll
    for (int j = 0; j < 2; ++j) {
      int col = col0 + wn * 32 + j * 16 + l15;
      int rbase = row0 + wm * 64 + i * 16 + l16 * 4;
      int ntok = ntok0 + wm * 64 + i * 16 + l16 * 4;
      if (flags == 2) {
        ushort4 pk = { f2bf(acc[i][j][0]), f2bf(acc[i][j][1]),
                       f2bf(acc[i][j][2]), f2bf(acc[i][j][3]) };
        *(ushort4*)&((ushort*)Cd)[((long)(btok * CDIM + col)) * 1024 + ntok] = pk;
      } else if (flags == 1) {
        ushort4 yv = *(const ushort4*)&ycr[((long)(btok * CDIM + col)) * 1024 + ntok];
        float bcol = bias[col];
        float* op = (float*)Cd;
        op[(long)(rbase + 0) * CDIM + col] = acc[i][j][0] + bcol + bf2f(yv.x);
        op[(long)(rbase + 1) * CDIM + col] = acc[i][j][1] + bcol + bf2f(yv.y);
        op[(long)(rbase + 2) * CDIM + col] = acc[i][j][2] + bcol + bf2f(yv.z);
        op[(long)(rbase + 3) * CDIM + col] = acc[i][j][3] + bcol + bf2f(yv.w);
      } else {
#pragma unroll
        for (int r = 0; r < 4; ++r)
          ((ushort*)Cd)[(long)(rbase + r) * CDIM + col] = f2bf(acc[i][j][r]);
      }
    }
}

// fused q/k/v projection GEMMs reading c-major conv outputs directly.
// z==2 (V) writes its output c-major.
__global__ __launch_bounds__(256) void gemm_qkv_k(
    const ushort* __restrict__ qc, const ushort* __restrict__ kc, const ushort* __restrict__ vc,
    const ushort* __restrict__ wqb, const ushort* __restrict__ wkb, const ushort* __restrict__ wvb,
    ushort* __restrict__ q1, ushort* __restrict__ k1, ushort* __restrict__ vtc)
{
  const int z = blockIdx.z;
  const ushort* A  = z == 0 ? qc  : z == 1 ? kc  : vc;
  const ushort* Wb = z == 0 ? wqb : z == 1 ? wkb : wvb;
  ushort*       C  = z == 0 ? q1  : z == 1 ? k1  : vtc;
  gemm_body<true>(A, Wb, nullptr, nullptr, C, z == 2 ? 2 : 0, blockIdx.x, blockIdx.y);
}

// final projection: out = A@wo^T + bo + x_fft (residual from yc)
__global__ __launch_bounds__(256) void gemm_out_k(
    const ushort* __restrict__ A, const ushort* __restrict__ Wb,
    const float* __restrict__ bias, const ushort* __restrict__ ycr,
    float* __restrict__ Cd)
{
  gemm_body<false>(A, Wb, bias, ycr, Cd, 1, blockIdx.x, blockIdx.y);
}

// ---------------------------------------------------------------------------
// Kernel 4: MFMA flash attention, TWO 64-row q-tiles per block (grid 64x8).
// K/V staging + barriers shared by 2x compute.  Swapped QK^T, cvt_pk P pack,
// no-max softmax, ones-MFMA row sums, Q direct from global, T14-lite reg
// prefetch of the next K/V tile.
// ---------------------------------------------------------------------------
__global__ __launch_bounds__(256) void attn_mfma_k(
    const ushort* __restrict__ q1, const ushort* __restrict__ k1,
    const ushort* __restrict__ vt, ushort* __restrict__ ao)
{
  const int bh = blockIdx.x, qt2 = blockIdx.y;
  const int b = bh >> 3, h = bh & 7;
  const int tid = threadIdx.x;
  const int w = tid >> 6, lane = tid & 63;
  const int l15 = lane & 15, l16 = lane >> 4;
  __shared__ ushort Ks[64][72], Vs[48][72], Ps[128][72];
  const float scale = 0.051031036307982884f;  // 384^-0.5
  const long base = (long)b * NPIX * CDIM + h * 48;
  const long vbase = (long)bh * 48 * NPIX;

  // per-thread staging descriptors (scalars -> no scratch).
  const int i0 = tid, i1 = tid + 256, i2 = tid + 512;
  const int r0 = i0 / 6, s0 = i0 - r0 * 6;
  const ushort* gp0 = k1 + base + (long)r0 * CDIM + s0 * 8;
  const long st0 = (long)64 * CDIM;
  ushort* lp0 = &Ks[r0][s0 * 8];
  const ushort* gp1; long st1; ushort* lp1;
  if (i1 < 384) {
    int r = i1 / 6, s = i1 - r * 6;
    gp1 = k1 + base + (long)r * CDIM + s * 8; st1 = (long)64 * CDIM; lp1 = &Ks[r][s * 8];
  } else {
    int j = i1 - 384, d = j >> 3, s = j & 7;
    gp1 = vt + vbase + (long)d * NPIX + s * 8; st1 = 64; lp1 = &Vs[d][s * 8];
  }
  const int j2 = i2 - 384, d2 = j2 >> 3, s2 = j2 & 7;
  const ushort* gp2 = vt + vbase + (long)d2 * NPIX + s2 * 8;
  const long st2 = 64;
  ushort* lp2 = &Vs[d2][s2 * 8];

  // zero K pad (cols 48..63), persists across iterations
  if (tid < 128) {
    uint4 z4 = {0u, 0u, 0u, 0u};
    int r = tid >> 1, s = tid & 1;
    *(uint4*)&Ks[r][48 + s * 8] = z4;
  }
  // Q fragments for both q-tile halves, direct from global
  const long qrowA = base + (long)(qt2 * 128 + w * 16 + l15) * CDIM;
  const long qrowB = qrowA + (long)64 * CDIM;
  short8v qa0A = *(const short8v*)&q1[qrowA + l16 * 8];
  short8v qa0B = *(const short8v*)&q1[qrowB + l16 * 8];
  short8v qa1A, qa1B;
  {
    short8v qz = {};
    short8v qvA = *(const short8v*)&q1[qrowA + ((l16 < 2) ? 32 + l16 * 8 : 0)];
    short8v qvB = *(const short8v*)&q1[qrowB + ((l16 < 2) ? 32 + l16 * 8 : 0)];
    qa1A = (l16 < 2) ? qvA : qz;
    qa1B = (l16 < 2) ? qvB : qz;
  }

  float lrunA[4] = {0.f, 0.f, 0.f, 0.f}, lrunB[4] = {0.f, 0.f, 0.f, 0.f};
  float4v accOA[3], accOB[3];
#pragma unroll
  for (int fd = 0; fd < 3; ++fd) {
    accOA[fd] = (float4v){0.f, 0.f, 0.f, 0.f};
    accOB[fd] = (float4v){0.f, 0.f, 0.f, 0.f};
  }
  short8v onesb;
#pragma unroll
  for (int j = 0; j < 8; ++j) onesb[j] = (short)0x3F80;  // bf16 1.0

  uint4 t0 = *(const uint4*)gp0;          // tile 0 loads
  uint4 t1 = *(const uint4*)gp1;
  uint4 t2 = *(const uint4*)gp2;

  for (int kt = 0; kt < 16; ++kt) {
    *(uint4*)lp0 = t0;
    *(uint4*)lp1 = t1;
    *(uint4*)lp2 = t2;
    __syncthreads();
    if (kt + 1 < 16) {                    // issue loads for t+1 under compute
      t0 = *(const uint4*)(gp0 + (long)(kt + 1) * st0);
      t1 = *(const uint4*)(gp1 + (long)(kt + 1) * st1);
      t2 = *(const uint4*)(gp2 + (long)(kt + 1) * st2);
    }
    // swapped QK^T for both halves: K frags loaded once
    float4v saccA[4], saccB[4];
#pragma unroll
    for (int fc = 0; fc < 4; ++fc) {
      short8v kb0 = *(const short8v*)&Ks[fc * 16 + l15][l16 * 8];
      short8v kb1 = *(const short8v*)&Ks[fc * 16 + l15][32 + l16 * 8];
      saccA[fc] = (float4v){0.f, 0.f, 0.f, 0.f};
      saccA[fc] = __builtin_amdgcn_mfma_f32_16x16x32_bf16(kb0, qa0A, saccA[fc], 0, 0, 0);
      saccA[fc] = __builtin_amdgcn_mfma_f32_16x16x32_bf16(kb1, qa1A, saccA[fc], 0, 0, 0);
      saccB[fc] = (float4v){0.f, 0.f, 0.f, 0.f};
      saccB[fc] = __builtin_amdgcn_mfma_f32_16x16x32_bf16(kb0, qa0B, saccB[fc], 0, 0, 0);
      saccB[fc] = __builtin_amdgcn_mfma_f32_16x16x32_bf16(kb1, qa1B, saccB[fc], 0, 0, 0);
    }
    // P = exp(S*scale); pack pairs -> dword stores (rows wave-private)
    unsigned* prowA = (unsigned*)&Ps[w * 16 + l15][0];
    unsigned* prowB = (unsigned*)&Ps[64 + w * 16 + l15][0];
#pragma unroll
    for (int fc = 0; fc < 4; ++fc) {
      float a0 = __expf(saccA[fc][0] * scale), a1 = __expf(saccA[fc][1] * scale);
      float a2 = __expf(saccA[fc][2] * scale), a3 = __expf(saccA[fc][3] * scale);
      __hip_bfloat162 dA01 = __float22bfloat162_rn(make_float2(a0, a1));
      __hip_bfloat162 dA23 = __float22bfloat162_rn(make_float2(a2, a3));
      prowA[fc * 8 + l16 * 2 + 0] = *(unsigned*)&dA01;
      prowA[fc * 8 + l16 * 2 + 1] = *(unsigned*)&dA23;
      float b0 = __expf(saccB[fc][0] * scale), b1 = __expf(saccB[fc][1] * scale);
      float b2 = __expf(saccB[fc][2] * scale), b3 = __expf(saccB[fc][3] * scale);
      __hip_bfloat162 dB01 = __float22bfloat162_rn(make_float2(b0, b1));
      __hip_bfloat162 dB23 = __float22bfloat162_rn(make_float2(b2, b3));
      prowB[fc * 8 + l16 * 2 + 0] = *(unsigned*)&dB01;
      prowB[fc * 8 + l16 * 2 + 1] = *(unsigned*)&dB23;
    }
    asm volatile("s_waitcnt lgkmcnt(0)" ::: "memory");
    __builtin_amdgcn_sched_barrier(0);
    short8v pa0A = *(const short8v*)&Ps[w * 16 + l15][l16 * 8];
    short8v pa1A = *(const short8v*)&Ps[w * 16 + l15][32 + l16 * 8];
    short8v pa0B = *(const short8v*)&Ps[64 + w * 16 + l15][l16 * 8];
    short8v pa1B = *(const short8v*)&Ps[64 + w * 16 + l15][32 + l16 * 8];
    // row sums via ones-MFMA
    float4v srA = (float4v){0.f, 0.f, 0.f, 0.f};
    srA = __builtin_amdgcn_mfma_f32_16x16x32_bf16(pa0A, onesb, srA, 0, 0, 0);
    srA = __builtin_amdgcn_mfma_f32_16x16x32_bf16(pa1A, onesb, srA, 0, 0, 0);
    float4v srB = (float4v){0.f, 0.f, 0.f, 0.f};
    srB = __builtin_amdgcn_mfma_f32_16x16x32_bf16(pa0B, onesb, srB, 0, 0, 0);
    srB = __builtin_amdgcn_mfma_f32_16x16x32_bf16(pa1B, onesb, srB, 0, 0, 0);
#pragma unroll
    for (int r = 0; r < 4; ++r) { lrunA[r] += srA[r]; lrunB[r] += srB[r]; }
    // PV for both halves; V frags loaded once
#pragma unroll
    for (int fd = 0; fd < 3; ++fd) {
      short8v vb0 = *(const short8v*)&Vs[fd * 16 + l15][l16 * 8];
      short8v vb1 = *(const short8v*)&Vs[fd * 16 + l15][32 + l16 * 8];
      accOA[fd] = __builtin_amdgcn_mfma_f32_16x16x32_bf16(pa0A, vb0, accOA[fd], 0, 0, 0);
      accOA[fd] = __builtin_amdgcn_mfma_f32_16x16x32_bf16(pa1A, vb1, accOA[fd], 0, 0, 0);
      accOB[fd] = __builtin_amdgcn_mfma_f32_16x16x32_bf16(pa0B, vb0, accOB[fd], 0, 0, 0);
      accOB[fd] = __builtin_amdgcn_mfma_f32_16x16x32_bf16(pa1B, vb1, accOB[fd], 0, 0, 0);
    }
    __syncthreads();                      // compute done; LDS free for t+1
  }
  float invA[4], invB[4];
#pragma unroll
  for (int r = 0; r < 4; ++r) { invA[r] = 1.f / lrunA[r]; invB[r] = 1.f / lrunB[r]; }
#pragma unroll
  for (int fd = 0; fd < 3; ++fd)
#pragma unroll
    for (int r = 0; r < 4; ++r) {
      int qrA = qt2 * 128 + w * 16 + l16 * 4 + r;
      ao[base + (long)qrA * CDIM + fd * 16 + l15] = f2bf(accOA[fd][r] * invA[r]);
      ao[base + (long)(qrA + 64) * CDIM + fd * 16 + l15] = f2bf(accOB[fd][r] * invB[r]);
    }
}

// ---------------------------------------------------------------------------
extern "C" void kernel_launch(void* const* d_in, const int* in_sizes, int n_in,
                              void* d_out, int out_size, void* d_ws, size_t ws_size,
                              hipStream_t stream) {
  const float* x   = (const float*)d_in[0];
  const float* cw  = (const float*)d_in[1];
  const float* dwq = (const float*)d_in[2];
  const float* dwk = (const float*)d_in[3];
  const float* dwv = (const float*)d_in[4];
  const float* gq  = (const float*)d_in[5];
  const float* bq  = (const float*)d_in[6];
  const float* mq  = (const float*)d_in[7];
  const float* vq  = (const float*)d_in[8];
  const float* gk  = (const float*)d_in[9];
  const float* bk  = (const float*)d_in[10];
  const float* mk  = (const float*)d_in[11];
  const float* vk  = (const float*)d_in[12];
  const float* gv  = (const float*)d_in[13];
  const float* bv  = (const float*)d_in[14];
  const float* mv  = (const float*)d_in[15];
  const float* vv  = (const float*)d_in[16];
  const float* wq  = (const float*)d_in[17];
  const float* wk  = (const float*)d_in[18];
  const float* wv  = (const float*)d_in[19];
  const float* wo  = (const float*)d_in[20];
  const float* bo  = (const float*)d_in[21];
  float* out = (float*)d_out;

  char* wsb = (char*)d_ws;
  const size_t H = (size_t)NB * NPIX * CDIM * 2;        // 6,291,456 B
  // slot plan (each H):
  // S0: xc -> vtc | S1: yc | S2: qc -> ao | S3: kc | S4: vc
  // S5: q1 | S6: k1 | S7: weights + tbl
  ushort* xcp = (ushort*)(wsb + 0 * H);
  ushort* vtc = (ushort*)(wsb + 0 * H);
  ushort* yc  = (ushort*)(wsb + 1 * H);
  ushort* qc  = (ushort*)(wsb + 2 * H);
  ushort* ao  = (ushort*)(wsb + 2 * H);
  ushort* kc  = (ushort*)(wsb + 3 * H);
  ushort* vc  = (ushort*)(wsb + 4 * H);
  ushort* q1  = (ushort*)(wsb + 5 * H);
  ushort* k1  = (ushort*)(wsb + 6 * H);
  ushort* wqb = (ushort*)(wsb + 7 * H);
  ushort* wkb = wqb + CDIM * CDIM;
  ushort* wvb = wkb + CDIM * CDIM;
  ushort* wob = wvb + CDIM * CDIM;
  ushort* tbl = wob + CDIM * CDIM;                      // 5*1024 ushorts

  prep_k<<<dim3(932), 256, 0, stream>>>(tbl, wq, wk, wv, wo,
      wqb, wkb, wvb, wob, x, xcp);
  fft_conv_k<<<dim3(NB * CDIM), 256, 0, stream>>>(xcp, cw, tbl, dwq, dwk, dwv,
      gq, bq, mq, vq, gk, bk, mk, vk, gv, bv, mv, vv, yc, qc, kc, vc);
  gemm_qkv_k<<<dim3(64, 6, 3), 256, 0, stream>>>(qc, kc, vc, wqb, wkb, wvb, q1, k1, vtc);
  attn_mfma_k<<<dim3(64, 8), 256, 0, stream>>>(q1, k1, vtc, ao);
  gemm_out_k<<<dim3(64, 6), 256, 0, stream>>>(ao, wob, bo, yc, out);
}

// Round 16
// 91.177 us; speedup vs baseline: 1.2307x; 1.1236x over previous
//
#include <hip/hip_runtime.h>
#include <hip/hip_bf16.h>
#include <cmath>

#define CDIM 384
#define NB 8
#define NPIX 1024

typedef __attribute__((ext_vector_type(8))) short short8v;
typedef __attribute__((ext_vector_type(4))) float float4v;

__device__ __forceinline__ ushort f2bf(float f) {
  union { float f; unsigned u; } v; v.f = f;
  unsigned r = (v.u + 0x7fffu + ((v.u >> 16) & 1u)) >> 16;
  return (ushort)r;
}
__device__ __forceinline__ float bf2f(ushort u) {
  union { unsigned u; float f; } v; v.u = ((unsigned)u) << 16;
  return v.f;
}

// ---------------------------------------------------------------------------
// Kernel 0 (merged): blocks 0..19 bf16 twiddle tables; 20..163 projection
// weights -> bf16; 164..931 x (b,n,c) f32 -> xc (b,c,n) bf16 transpose.
// ---------------------------------------------------------------------------
__global__ __launch_bounds__(256) void prep_k(
    ushort* __restrict__ tbl,
    const float* __restrict__ wq, const float* __restrict__ wk,
    const float* __restrict__ wv, const float* __restrict__ wo,
    ushort* __restrict__ wqb, ushort* __restrict__ wkb,
    ushort* __restrict__ wvb, ushort* __restrict__ wob,
    const float* __restrict__ x, ushort* __restrict__ xc)
{
  __shared__ ushort T[128][33];
  if (blockIdx.x < 20) {
    int i = blockIdx.x * 256 + threadIdx.x;
    if (i >= 5 * 1024) return;
    int t = i >> 10, j = i & 1023, r = j >> 5, cidx = j & 31;
    float ang = (float)((r * cidx) & 31) * 0.19634954084936207f;
    float val;
    if (t == 0) val = cosf(ang);
    else if (t == 1) val = sinf(ang);
    else if (t == 2) val = -sinf(ang);
    else {
      if (cidx > 16) val = 0.f;
      else {
        float cv = (cidx == 0 || cidx == 16) ? 1.f : 2.f;
        val = (t == 3) ? cv * cosf(ang) : -cv * sinf(ang);
      }
    }
    tbl[i] = f2bf(val);
  } else if (blockIdx.x < 164) {
    int i = (blockIdx.x - 20) * 256 + threadIdx.x;
    if (i * 4 >= CDIM * CDIM) return;
    float4 va = *(const float4*)&wq[i * 4];
    float4 vb = *(const float4*)&wk[i * 4];
    float4 vc = *(const float4*)&wv[i * 4];
    float4 vd = *(const float4*)&wo[i * 4];
    ushort4 ra = { f2bf(va.x), f2bf(va.y), f2bf(va.z), f2bf(va.w) };
    ushort4 rb = { f2bf(vb.x), f2bf(vb.y), f2bf(vb.z), f2bf(vb.w) };
    ushort4 rc = { f2bf(vc.x), f2bf(vc.y), f2bf(vc.z), f2bf(vc.w) };
    ushort4 rd = { f2bf(vd.x), f2bf(vd.y), f2bf(vd.z), f2bf(vd.w) };
    *(ushort4*)&wqb[i * 4] = ra;
    *(ushort4*)&wkb[i * 4] = rb;
    *(ushort4*)&wvb[i * 4] = rc;
    *(ushort4*)&wob[i * 4] = rd;
  } else {
    int t = blockIdx.x - 164;             // 768 blocks: b*96 + (c0/32)*8 + n0/128
    int b = t / 96, rr = t % 96;
    int c0 = (rr >> 3) * 32, n0 = (rr & 7) * 128;
    for (int i = threadIdx.x; i < 4096; i += 256) {
      int n = i >> 5, c = i & 31;
      T[n][c] = f2bf(x[((long)(b * 1024 + n0 + n)) * CDIM + c0 + c]);
    }
    __syncthreads();
    for (int i = threadIdx.x; i < 4096; i += 256) {
      int c = i >> 7, n = i & 127;
      xc[((long)(b * CDIM + c0 + c)) * 1024 + n0 + n] = T[n][c];
    }
  }
}

// ---------------------------------------------------------------------------
// Kernel 1: spectral filter via MFMA + FUSED depthwise conv3x3 + BN.
// ONE channel per block (32KB LDS, high occupancy).
// ---------------------------------------------------------------------------
__global__ __launch_bounds__(256) void fft_conv_k(
    const ushort* __restrict__ xc, const float* __restrict__ cw,
    const ushort* __restrict__ tbl,
    const float* __restrict__ dwq, const float* __restrict__ dwk, const float* __restrict__ dwv,
    const float* __restrict__ gq, const float* __restrict__ bq, const float* __restrict__ mq, const float* __restrict__ vq,
    const float* __restrict__ gk, const float* __restrict__ bk, const float* __restrict__ mk, const float* __restrict__ vk,
    const float* __restrict__ gv, const float* __restrict__ bv, const float* __restrict__ mv, const float* __restrict__ vv,
    ushort* __restrict__ yc,
    ushort* __restrict__ qc, ushort* __restrict__ kc, ushort* __restrict__ vc)
{
  const int b = blockIdx.x / CDIM, c = blockIdx.x % CDIM;
  const int tid = threadIdx.x;
  const int w = tid >> 6, lane = tid & 63;
  const int l15 = lane & 15, l16 = lane >> 4;
  __shared__ ushort B[11][32][40];
  __shared__ float Ysf[32][33];

  float wq9[9], wk9[9], wv9[9];
#pragma unroll
  for (int t = 0; t < 9; ++t) {
    wq9[t] = dwq[c * 9 + t];
    wk9[t] = dwk[c * 9 + t];
    wv9[t] = dwv[c * 9 + t];
  }
  float scq = gq[c] * rsqrtf(vq[c] + 1e-5f); float shq = bq[c] - mq[c] * scq;
  float sck = gk[c] * rsqrtf(vk[c] + 1e-5f); float shk = bk[c] - mk[c] * sck;
  float scv = gv[c] * rsqrtf(vv[c] + 1e-5f); float shv = bv[c] - mv[c] * scv;

  for (int i = tid; i < 640; i += 256) {                 // tables -> LDS
    int t = i >> 7, j = i & 127, r = j >> 2, s = j & 3;
    *(uint4*)&B[t][r][s * 8] = *(const uint4*)&tbl[t * 1024 + r * 32 + s * 8];
  }
  for (int i = tid; i < 1024; i += 256)                  // input -> Xt[w][h]
    B[5][i & 31][i >> 5] = xc[(long)(b * CDIM + c) * 1024 + i];
  __syncthreads();

  // stage1: R1[u,w] = sum_h Tc[u,h]*Xt[w,h];  I1 = sum_h Tsn[u,h]*Xt[w,h]
  for (int j = w; j < 8; j += 4) {
    int o = j & 1, ut = (j >> 1) & 1, wt = (j >> 2) & 1;
    short8v af = *(const short8v*)&B[o == 0 ? 0 : 2][ut * 16 + l15][l16 * 8];
    short8v bf = *(const short8v*)&B[5][wt * 16 + l15][l16 * 8];
    float4v acc = {0.f, 0.f, 0.f, 0.f};
    acc = __builtin_amdgcn_mfma_f32_16x16x32_bf16(af, bf, acc, 0, 0, 0);
    int dst = (o == 0) ? 7 : 8;
#pragma unroll
    for (int r = 0; r < 4; ++r)
      B[dst][ut * 16 + l16 * 4 + r][wt * 16 + l15] = f2bf(acc[r]);
  }
  __syncthreads();

  // stage2: Xfr[u,v] = R1.Tc + I1.Ts ; Xfi = I1.Tc + R1.Tsn  (fp32 raw store)
  for (int j = w; j < 8; j += 4) {
    int o = j & 1, ut = (j >> 1) & 1, vt = (j >> 2) & 1;
    short8v a1 = *(const short8v*)&B[o == 0 ? 7 : 8][ut * 16 + l15][l16 * 8];
    short8v b1 = *(const short8v*)&B[0][vt * 16 + l15][l16 * 8];
    short8v a2 = *(const short8v*)&B[o == 0 ? 8 : 7][ut * 16 + l15][l16 * 8];
    short8v b2 = *(const short8v*)&B[o == 0 ? 1 : 2][vt * 16 + l15][l16 * 8];
    float4v acc = {0.f, 0.f, 0.f, 0.f};
    acc = __builtin_amdgcn_mfma_f32_16x16x32_bf16(a1, b1, acc, 0, 0, 0);
    acc = __builtin_amdgcn_mfma_f32_16x16x32_bf16(a2, b2, acc, 0, 0, 0);
    int v = vt * 16 + l15;
    if (v < 17) {
      float* praw = (float*)&B[o == 0 ? 5 : 6][0][0];    // [32][20] f32 view
#pragma unroll
      for (int r = 0; r < 4; ++r)
        praw[(ut * 16 + l16 * 4 + r) * 20 + v] = acc[r];
    }
  }
  __syncthreads();

  // zero Ytr/Yti rows 17..31, then weight-multiply + transpose scatter
  for (int i = tid; i < 150; i += 256) {
    int buf = i / 75, j2 = i % 75, r2 = 17 + j2 / 5, s2 = j2 % 5;
    uint4 z = {0u, 0u, 0u, 0u};
    *(uint4*)&B[9 + buf][r2][s2 * 8] = z;
  }
  {
    const float* xfr = (const float*)&B[5][0][0];
    const float* xfi = (const float*)&B[6][0][0];
    for (int e = tid; e < 544; e += 256) {
      int u = e / 17, v = e - u * 17;
      float fr = xfr[u * 20 + v], fi = xfi[u * 20 + v];
      float2 wc = *(const float2*)&cw[((long)(c * 32 + u) * 17 + v) * 2];
      B[9][v][u]  = f2bf(fr * wc.x - fi * wc.y);
      B[10][v][u] = f2bf(fr * wc.y + fi * wc.x);
    }
  }
  __syncthreads();

  // stage3: Zr[h,v] = Tc(h).Ytr + Tsn(h).Yti ; Zi = Tc(h).Yti + Ts(h).Ytr
  for (int j = w; j < 8; j += 4) {
    int o = j & 1, ht = (j >> 1) & 1, vt = (j >> 2) & 1;
    short8v a1 = *(const short8v*)&B[0][ht * 16 + l15][l16 * 8];
    short8v b1 = *(const short8v*)&B[o == 0 ? 9 : 10][vt * 16 + l15][l16 * 8];
    short8v a2 = *(const short8v*)&B[o == 0 ? 2 : 1][ht * 16 + l15][l16 * 8];
    short8v b2 = *(const short8v*)&B[o == 0 ? 10 : 9][vt * 16 + l15][l16 * 8];
    float4v acc = {0.f, 0.f, 0.f, 0.f};
    acc = __builtin_amdgcn_mfma_f32_16x16x32_bf16(a1, b1, acc, 0, 0, 0);
    acc = __builtin_amdgcn_mfma_f32_16x16x32_bf16(a2, b2, acc, 0, 0, 0);
    int dst = (o == 0) ? 7 : 8;
#pragma unroll
    for (int r = 0; r < 4; ++r)
      B[dst][ht * 16 + l16 * 4 + r][vt * 16 + l15] = f2bf(acc[r]);
  }
  __syncthreads();

  // stage4: y[h,w] = (Zr.Uc^T + Zi.Us^T)/1024 -> Ysf (LDS) + yc (coalesced)
  {
    int ht = w & 1, wt = (w >> 1) & 1;
    short8v a1 = *(const short8v*)&B[7][ht * 16 + l15][l16 * 8];
    short8v b1 = *(const short8v*)&B[3][wt * 16 + l15][l16 * 8];
    short8v a2 = *(const short8v*)&B[8][ht * 16 + l15][l16 * 8];
    short8v b2 = *(const short8v*)&B[4][wt * 16 + l15][l16 * 8];
    float4v acc = {0.f, 0.f, 0.f, 0.f};
    acc = __builtin_amdgcn_mfma_f32_16x16x32_bf16(a1, b1, acc, 0, 0, 0);
    acc = __builtin_amdgcn_mfma_f32_16x16x32_bf16(a2, b2, acc, 0, 0, 0);
#pragma unroll
    for (int r = 0; r < 4; ++r) {
      int hh = ht * 16 + l16 * 4 + r, ww = wt * 16 + l15;
      float y = acc[r] * (1.0f / 1024.0f);
      Ysf[hh][ww] = y;
      yc[(long)(b * CDIM + c) * 1024 + hh * 32 + ww] = f2bf(y);
    }
  }
  __syncthreads();

  // fused depthwise 3x3 conv + BN -> qc/kc/vc (bf16, b,c,n — coalesced)
  for (int i = tid; i < 1024; i += 256) {
    int hh = i >> 5, ww = i & 31;
    float aq = 0.f, ak = 0.f, av = 0.f;
#pragma unroll
    for (int dy = 0; dy < 3; ++dy) {
      int y0 = hh + dy - 1;
#pragma unroll
      for (int dx = 0; dx < 3; ++dx) {
        int x0 = ww + dx - 1;
        float xv = (y0 >= 0 && y0 < 32 && x0 >= 0 && x0 < 32) ? Ysf[y0][x0] : 0.f;
        int t = dy * 3 + dx;
        aq += xv * wq9[t]; ak += xv * wk9[t]; av += xv * wv9[t];
      }
    }
    long o = (long)(b * CDIM + c) * 1024 + i;
    qc[o] = f2bf(aq * scq + shq);
    kc[o] = f2bf(ak * sck + shk);
    vc[o] = f2bf(av * scv + shv);
  }
}

// ---------------------------------------------------------------------------
// MFMA GEMM body  C[m,n'] = sum_k A[m,k] W[n',k]
// tile 128x64, BK=64, 4 waves (2x2), padded LDS (stride 72 bf16 = 144B).
// T14-lite software pipeline: global loads for K-step t+1 issued (into
// scalar regs) right after the staging barrier, hidden under compute(t).
// CMA=true: A is c-major (b,c,n); staging does the n<->c transpose in LDS
//   with a row-XOR column swizzle (col ^ (row&56)).
// flags==0: bf16 store (n-major).  flags==1: fp32 write out = acc+bias+y
// (residual from ycr, c-major bf16).  flags==2: bf16 store c-major (ushort4).
// ---------------------------------------------------------------------------
template<bool CMA>
__device__ __forceinline__ void gemm_body(
    const ushort* __restrict__ A, const ushort* __restrict__ Wb,
    const float* __restrict__ bias, const ushort* __restrict__ ycr,
    void* __restrict__ Cd, int flags, int bx, int by)
{
  __shared__ ushort As[128][72];
  __shared__ ushort Ws[64][72];
  const int tid = threadIdx.x;
  const int w = tid >> 6, lane = tid & 63;
  const int l15 = lane & 15, l16 = lane >> 4;
  const int wm = w >> 1, wn = w & 1;
  const int row0 = bx * 128, col0 = by * 64;
  const int btok = row0 >> 10;           // batch index
  const int ntok0 = row0 & 1023;
  const int ra = tid >> 3, sa8 = (tid & 7) * 8;   // staging coords
  const int g = tid & 15, u4 = (tid >> 4) * 4;     // CMA staging coords
  const int colu = u4 ^ ((g & 7) << 3);
  float4v acc[4][2];
#pragma unroll
  for (int i = 0; i < 4; ++i)
#pragma unroll
    for (int j = 0; j < 2; ++j) acc[i][j] = (float4v){0.f, 0.f, 0.f, 0.f};

  uint4 a0, a1, a2, a3, w0, w1;
#define GLOAD(KT) do { \
    if (CMA) { \
      const long ab = ((long)(btok * CDIM + (KT) + u4)) * 1024 + ntok0 + g * 8; \
      a0 = *(const uint4*)&A[ab + 0 * 1024]; \
      a1 = *(const uint4*)&A[ab + 1 * 1024]; \
      a2 = *(const uint4*)&A[ab + 2 * 1024]; \
      a3 = *(const uint4*)&A[ab + 3 * 1024]; \
    } else { \
      const long ab = (long)(row0 + ra) * CDIM + (KT) + sa8; \
      a0 = *(const uint4*)&A[ab + (long)0 * 32 * CDIM]; \
      a1 = *(const uint4*)&A[ab + (long)1 * 32 * CDIM]; \
      a2 = *(const uint4*)&A[ab + (long)2 * 32 * CDIM]; \
      a3 = *(const uint4*)&A[ab + (long)3 * 32 * CDIM]; \
    } \
    const long wb = (long)(col0 + ra) * CDIM + (KT) + sa8; \
    w0 = *(const uint4*)&Wb[wb]; \
    w1 = *(const uint4*)&Wb[wb + (long)32 * CDIM]; } while (0)

#define LWRITE() do { \
    if (CMA) { \
      const ushort* s0 = (const ushort*)&a0; \
      const ushort* s1 = (const ushort*)&a1; \
      const ushort* s2 = (const ushort*)&a2; \
      const ushort* s3 = (const ushort*)&a3; \
      _Pragma("unroll") \
      for (int i = 0; i < 8; ++i) { \
        uint2 wv; \
        wv.x = (unsigned)s0[i] | ((unsigned)s1[i] << 16); \
        wv.y = (unsigned)s2[i] | ((unsigned)s3[i] << 16); \
        *(uint2*)&As[g * 8 + i][colu] = wv; \
      } \
    } else { \
      *(uint4*)&As[ra +  0][sa8] = a0; \
      *(uint4*)&As[ra + 32][sa8] = a1; \
      *(uint4*)&As[ra + 64][sa8] = a2; \
      *(uint4*)&As[ra + 96][sa8] = a3; \
    } \
    *(uint4*)&Ws[ra][sa8] = w0; \
    *(uint4*)&Ws[ra + 32][sa8] = w1; } while (0)

  GLOAD(0);
  for (int kt = 0; kt < CDIM; kt += 64) {
    LWRITE();
    __syncthreads();
    if (kt + 64 < CDIM) GLOAD(kt + 64);  // hidden under compute
#pragma unroll
    for (int s = 0; s < 2; ++s) {
      short8v a[4], bfr[2];
#pragma unroll
      for (int i = 0; i < 4; ++i) {
        int arow = wm * 64 + i * 16 + l15;
        int acol = s * 32 + l16 * 8;
        if (CMA) acol ^= (arow & 56);
        a[i] = *(const short8v*)&As[arow][acol];
      }
#pragma unroll
      for (int j = 0; j < 2; ++j)
        bfr[j] = *(const short8v*)&Ws[wn * 32 + j * 16 + l15][s * 32 + l16 * 8];
#pragma unroll
      for (int i = 0; i < 4; ++i)
#pragma unroll
        for (int j = 0; j < 2; ++j)
          acc[i][j] = __builtin_amdgcn_mfma_f32_16x16x32_bf16(a[i], bfr[j], acc[i][j], 0, 0, 0);
    }
    if (kt + 64 < CDIM) __syncthreads();
  }
#undef GLOAD
#undef LWRITE
#pragma unroll
  for (int i = 0; i < 4; ++i)
#pragma unroll
    for (int j = 0; j < 2; ++j) {
      int col = col0 + wn * 32 + j * 16 + l15;
      int rbase = row0 + wm * 64 + i * 16 + l16 * 4;
      int ntok = ntok0 + wm * 64 + i * 16 + l16 * 4;
      if (flags == 2) {
        ushort4 pk = { f2bf(acc[i][j][0]), f2bf(acc[i][j][1]),
                       f2bf(acc[i][j][2]), f2bf(acc[i][j][3]) };
        *(ushort4*)&((ushort*)Cd)[((long)(btok * CDIM + col)) * 1024 + ntok] = pk;
      } else if (flags == 1) {
        ushort4 yv = *(const ushort4*)&ycr[((long)(btok * CDIM + col)) * 1024 + ntok];
        float bcol = bias[col];
        float* op = (float*)Cd;
        op[(long)(rbase + 0) * CDIM + col] = acc[i][j][0] + bcol + bf2f(yv.x);
        op[(long)(rbase + 1) * CDIM + col] = acc[i][j][1] + bcol + bf2f(yv.y);
        op[(long)(rbase + 2) * CDIM + col] = acc[i][j][2] + bcol + bf2f(yv.z);
        op[(long)(rbase + 3) * CDIM + col] = acc[i][j][3] + bcol + bf2f(yv.w);
      } else {
#pragma unroll
        for (int r = 0; r < 4; ++r)
          ((ushort*)Cd)[(long)(rbase + r) * CDIM + col] = f2bf(acc[i][j][r]);
      }
    }
}

// fused q/k/v projection GEMMs reading c-major conv outputs directly.
// z==2 (V) writes its output c-major.
__global__ __launch_bounds__(256) void gemm_qkv_k(
    const ushort* __restrict__ qc, const ushort* __restrict__ kc, const ushort* __restrict__ vc,
    const ushort* __restrict__ wqb, const ushort* __restrict__ wkb, const ushort* __restrict__ wvb,
    ushort* __restrict__ q1, ushort* __restrict__ k1, ushort* __restrict__ vtc)
{
  const int z = blockIdx.z;
  const ushort* A  = z == 0 ? qc  : z == 1 ? kc  : vc;
  const ushort* Wb = z == 0 ? wqb : z == 1 ? wkb : wvb;
  ushort*       C  = z == 0 ? q1  : z == 1 ? k1  : vtc;
  gemm_body<true>(A, Wb, nullptr, nullptr, C, z == 2 ? 2 : 0, blockIdx.x, blockIdx.y);
}

// final projection: out = A@wo^T + bo + x_fft (residual from yc)
__global__ __launch_bounds__(256) void gemm_out_k(
    const ushort* __restrict__ A, const ushort* __restrict__ Wb,
    const float* __restrict__ bias, const ushort* __restrict__ ycr,
    float* __restrict__ Cd)
{
  gemm_body<false>(A, Wb, bias, ycr, Cd, 1, blockIdx.x, blockIdx.y);
}

// ---------------------------------------------------------------------------
// Kernel 4: MFMA flash attention, TWO 64-row q-tiles per block (grid 64x8).
// K/V staging + barriers shared by 2x compute.  Swapped QK^T, cvt_pk P pack,
// no-max softmax, ones-MFMA row sums, Q direct from global, T14-lite reg
// prefetch of the next K/V tile.
// ---------------------------------------------------------------------------
__global__ __launch_bounds__(256) void attn_mfma_k(
    const ushort* __restrict__ q1, const ushort* __restrict__ k1,
    const ushort* __restrict__ vt, ushort* __restrict__ ao)
{
  const int bh = blockIdx.x, qt2 = blockIdx.y;
  const int b = bh >> 3, h = bh & 7;
  const int tid = threadIdx.x;
  const int w = tid >> 6, lane = tid & 63;
  const int l15 = lane & 15, l16 = lane >> 4;
  __shared__ ushort Ks[64][72], Vs[48][72], Ps[128][72];
  const float scale = 0.051031036307982884f;  // 384^-0.5
  const long base = (long)b * NPIX * CDIM + h * 48;
  const long vbase = (long)bh * 48 * NPIX;

  // per-thread staging descriptors (scalars -> no scratch).
  const int i0 = tid, i1 = tid + 256, i2 = tid + 512;
  const int r0 = i0 / 6, s0 = i0 - r0 * 6;
  const ushort* gp0 = k1 + base + (long)r0 * CDIM + s0 * 8;
  const long st0 = (long)64 * CDIM;
  ushort* lp0 = &Ks[r0][s0 * 8];
  const ushort* gp1; long st1; ushort* lp1;
  if (i1 < 384) {
    int r = i1 / 6, s = i1 - r * 6;
    gp1 = k1 + base + (long)r * CDIM + s * 8; st1 = (long)64 * CDIM; lp1 = &Ks[r][s * 8];
  } else {
    int j = i1 - 384, d = j >> 3, s = j & 7;
    gp1 = vt + vbase + (long)d * NPIX + s * 8; st1 = 64; lp1 = &Vs[d][s * 8];
  }
  const int j2 = i2 - 384, d2 = j2 >> 3, s2 = j2 & 7;
  const ushort* gp2 = vt + vbase + (long)d2 * NPIX + s2 * 8;
  const long st2 = 64;
  ushort* lp2 = &Vs[d2][s2 * 8];

  // zero K pad (cols 48..63), persists across iterations
  if (tid < 128) {
    uint4 z4 = {0u, 0u, 0u, 0u};
    int r = tid >> 1, s = tid & 1;
    *(uint4*)&Ks[r][48 + s * 8] = z4;
  }
  // Q fragments for both q-tile halves, direct from global
  const long qrowA = base + (long)(qt2 * 128 + w * 16 + l15) * CDIM;
  const long qrowB = qrowA + (long)64 * CDIM;
  short8v qa0A = *(const short8v*)&q1[qrowA + l16 * 8];
  short8v qa0B = *(const short8v*)&q1[qrowB + l16 * 8];
  short8v qa1A, qa1B;
  {
    short8v qz = {};
    short8v qvA = *(const short8v*)&q1[qrowA + ((l16 < 2) ? 32 + l16 * 8 : 0)];
    short8v qvB = *(const short8v*)&q1[qrowB + ((l16 < 2) ? 32 + l16 * 8 : 0)];
    qa1A = (l16 < 2) ? qvA : qz;
    qa1B = (l16 < 2) ? qvB : qz;
  }

  float lrunA[4] = {0.f, 0.f, 0.f, 0.f}, lrunB[4] = {0.f, 0.f, 0.f, 0.f};
  float4v accOA[3], accOB[3];
#pragma unroll
  for (int fd = 0; fd < 3; ++fd) {
    accOA[fd] = (float4v){0.f, 0.f, 0.f, 0.f};
    accOB[fd] = (float4v){0.f, 0.f, 0.f, 0.f};
  }
  short8v onesb;
#pragma unroll
  for (int j = 0; j < 8; ++j) onesb[j] = (short)0x3F80;  // bf16 1.0

  uint4 t0 = *(const uint4*)gp0;          // tile 0 loads
  uint4 t1 = *(const uint4*)gp1;
  uint4 t2 = *(const uint4*)gp2;

  for (int kt = 0; kt < 16; ++kt) {
    *(uint4*)lp0 = t0;
    *(uint4*)lp1 = t1;
    *(uint4*)lp2 = t2;
    __syncthreads();
    if (kt + 1 < 16) {                    // issue loads for t+1 under compute
      t0 = *(const uint4*)(gp0 + (long)(kt + 1) * st0);
      t1 = *(const uint4*)(gp1 + (long)(kt + 1) * st1);
      t2 = *(const uint4*)(gp2 + (long)(kt + 1) * st2);
    }
    // swapped QK^T for both halves: K frags loaded once
    float4v saccA[4], saccB[4];
#pragma unroll
    for (int fc = 0; fc < 4; ++fc) {
      short8v kb0 = *(const short8v*)&Ks[fc * 16 + l15][l16 * 8];
      short8v kb1 = *(const short8v*)&Ks[fc * 16 + l15][32 + l16 * 8];
      saccA[fc] = (float4v){0.f, 0.f, 0.f, 0.f};
      saccA[fc] = __builtin_amdgcn_mfma_f32_16x16x32_bf16(kb0, qa0A, saccA[fc], 0, 0, 0);
      saccA[fc] = __builtin_amdgcn_mfma_f32_16x16x32_bf16(kb1, qa1A, saccA[fc], 0, 0, 0);
      saccB[fc] = (float4v){0.f, 0.f, 0.f, 0.f};
      saccB[fc] = __builtin_amdgcn_mfma_f32_16x16x32_bf16(kb0, qa0B, saccB[fc], 0, 0, 0);
      saccB[fc] = __builtin_amdgcn_mfma_f32_16x16x32_bf16(kb1, qa1B, saccB[fc], 0, 0, 0);
    }
    // P = exp(S*scale); pack pairs -> dword stores (rows wave-private)
    unsigned* prowA = (unsigned*)&Ps[w * 16 + l15][0];
    unsigned* prowB = (unsigned*)&Ps[64 + w * 16 + l15][0];
#pragma unroll
    for (int fc = 0; fc < 4; ++fc) {
      float a0 = __expf(saccA[fc][0] * scale), a1 = __expf(saccA[fc][1] * scale);
      float a2 = __expf(saccA[fc][2] * scale), a3 = __expf(saccA[fc][3] * scale);
      __hip_bfloat162 dA01 = __float22bfloat162_rn(make_float2(a0, a1));
      __hip_bfloat162 dA23 = __float22bfloat162_rn(make_float2(a2, a3));
      prowA[fc * 8 + l16 * 2 + 0] = *(unsigned*)&dA01;
      prowA[fc * 8 + l16 * 2 + 1] = *(unsigned*)&dA23;
      float b0 = __expf(saccB[fc][0] * scale), b1 = __expf(saccB[fc][1] * scale);
      float b2 = __expf(saccB[fc][2] * scale), b3 = __expf(saccB[fc][3] * scale);
      __hip_bfloat162 dB01 = __float22bfloat162_rn(make_float2(b0, b1));
      __hip_bfloat162 dB23 = __float22bfloat162_rn(make_float2(b2, b3));
      prowB[fc * 8 + l16 * 2 + 0] = *(unsigned*)&dB01;
      prowB[fc * 8 + l16 * 2 + 1] = *(unsigned*)&dB23;
    }
    asm volatile("s_waitcnt lgkmcnt(0)" ::: "memory");
    __builtin_amdgcn_sched_barrier(0);
    short8v pa0A = *(const short8v*)&Ps[w * 16 + l15][l16 * 8];
    short8v pa1A = *(const short8v*)&Ps[w * 16 + l15][32 + l16 * 8];
    short8v pa0B = *(const short8v*)&Ps[64 + w * 16 + l15][l16 * 8];
    short8v pa1B = *(const short8v*)&Ps[64 + w * 16 + l15][32 + l16 * 8];
    // row sums via ones-MFMA
    float4v srA = (float4v){0.f, 0.f, 0.f, 0.f};
    srA = __builtin_amdgcn_mfma_f32_16x16x32_bf16(pa0A, onesb, srA, 0, 0, 0);
    srA = __builtin_amdgcn_mfma_f32_16x16x32_bf16(pa1A, onesb, srA, 0, 0, 0);
    float4v srB = (float4v){0.f, 0.f, 0.f, 0.f};
    srB = __builtin_amdgcn_mfma_f32_16x16x32_bf16(pa0B, onesb, srB, 0, 0, 0);
    srB = __builtin_amdgcn_mfma_f32_16x16x32_bf16(pa1B, onesb, srB, 0, 0, 0);
#pragma unroll
    for (int r = 0; r < 4; ++r) { lrunA[r] += srA[r]; lrunB[r] += srB[r]; }
    // PV for both halves; V frags loaded once
#pragma unroll
    for (int fd = 0; fd < 3; ++fd) {
      short8v vb0 = *(const short8v*)&Vs[fd * 16 + l15][l16 * 8];
      short8v vb1 = *(const short8v*)&Vs[fd * 16 + l15][32 + l16 * 8];
      accOA[fd] = __builtin_amdgcn_mfma_f32_16x16x32_bf16(pa0A, vb0, accOA[fd], 0, 0, 0);
      accOA[fd] = __builtin_amdgcn_mfma_f32_16x16x32_bf16(pa1A, vb1, accOA[fd], 0, 0, 0);
      accOB[fd] = __builtin_amdgcn_mfma_f32_16x16x32_bf16(pa0B, vb0, accOB[fd], 0, 0, 0);
      accOB[fd] = __builtin_amdgcn_mfma_f32_16x16x32_bf16(pa1B, vb1, accOB[fd], 0, 0, 0);
    }
    __syncthreads();                      // compute done; LDS free for t+1
  }
  float invA[4], invB[4];
#pragma unroll
  for (int r = 0; r < 4; ++r) { invA[r] = 1.f / lrunA[r]; invB[r] = 1.f / lrunB[r]; }
#pragma unroll
  for (int fd = 0; fd < 3; ++fd)
#pragma unroll
    for (int r = 0; r < 4; ++r) {
      int qrA = qt2 * 128 + w * 16 + l16 * 4 + r;
      ao[base + (long)qrA * CDIM + fd * 16 + l15] = f2bf(accOA[fd][r] * invA[r]);
      ao[base + (long)(qrA + 64) * CDIM + fd * 16 + l15] = f2bf(accOB[fd][r] * invB[r]);
    }
}

// ---------------------------------------------------------------------------
extern "C" void kernel_launch(void* const* d_in, const int* in_sizes, int n_in,
                              void* d_out, int out_size, void* d_ws, size_t ws_size,
                              hipStream_t stream) {
  const float* x   = (const float*)d_in[0];
  const float* cw  = (const float*)d_in[1];
  const float* dwq = (const float*)d_in[2];
  const float* dwk = (const float*)d_in[3];
  const float* dwv = (const float*)d_in[4];
  const float* gq  = (const float*)d_in[5];
  const float* bq  = (const float*)d_in[6];
  const float* mq  = (const float*)d_in[7];
  const float* vq  = (const float*)d_in[8];
  const float* gk  = (const float*)d_in[9];
  const float* bk  = (const float*)d_in[10];
  const float* mk  = (const float*)d_in[11];
  const float* vk  = (const float*)d_in[12];
  const float* gv  = (const float*)d_in[13];
  const float* bv  = (const float*)d_in[14];
  const float* mv  = (const float*)d_in[15];
  const float* vv  = (const float*)d_in[16];
  const float* wq  = (const float*)d_in[17];
  const float* wk  = (const float*)d_in[18];
  const float* wv  = (const float*)d_in[19];
  const float* wo  = (const float*)d_in[20];
  const float* bo  = (const float*)d_in[21];
  float* out = (float*)d_out;

  char* wsb = (char*)d_ws;
  const size_t H = (size_t)NB * NPIX * CDIM * 2;        // 6,291,456 B
  // slot plan (each H):
  // S0: xc -> vtc | S1: yc | S2: qc -> ao | S3: kc | S4: vc
  // S5: q1 | S6: k1 | S7: weights + tbl
  ushort* xcp = (ushort*)(wsb + 0 * H);
  ushort* vtc = (ushort*)(wsb + 0 * H);
  ushort* yc  = (ushort*)(wsb + 1 * H);
  ushort* qc  = (ushort*)(wsb + 2 * H);
  ushort* ao  = (ushort*)(wsb + 2 * H);
  ushort* kc  = (ushort*)(wsb + 3 * H);
  ushort* vc  = (ushort*)(wsb + 4 * H);
  ushort* q1  = (ushort*)(wsb + 5 * H);
  ushort* k1  = (ushort*)(wsb + 6 * H);
  ushort* wqb = (ushort*)(wsb + 7 * H);
  ushort* wkb = wqb + CDIM * CDIM;
  ushort* wvb = wkb + CDIM * CDIM;
  ushort* wob = wvb + CDIM * CDIM;
  ushort* tbl = wob + CDIM * CDIM;                      // 5*1024 ushorts

  prep_k<<<dim3(932), 256, 0, stream>>>(tbl, wq, wk, wv, wo,
      wqb, wkb, wvb, wob, x, xcp);
  fft_conv_k<<<dim3(NB * CDIM), 256, 0, stream>>>(xcp, cw, tbl, dwq, dwk, dwv,
      gq, bq, mq, vq, gk, bk, mk, vk, gv, bv, mv, vv, yc, qc, kc, vc);
  gemm_qkv_k<<<dim3(64, 6, 3), 256, 0, stream>>>(qc, kc, vc, wqb, wkb, wvb, q1, k1, vtc);
  attn_mfma_k<<<dim3(64, 8), 256, 0, stream>>>(q1, k1, vtc, ao);
  gemm_out_k<<<dim3(64, 6), 256, 0, stream>>>(ao, wob, bo, yc, out);
}

// Round 17
// 88.151 us; speedup vs baseline: 1.2729x; 1.0343x over previous
//
#include <hip/hip_runtime.h>
#include <hip/hip_bf16.h>
#include <cmath>

#define CDIM 384
#define NB 8
#define NPIX 1024

typedef __attribute__((ext_vector_type(8))) short short8v;
typedef __attribute__((ext_vector_type(4))) float float4v;

__device__ __forceinline__ ushort f2bf(float f) {
  union { float f; unsigned u; } v; v.f = f;
  unsigned r = (v.u + 0x7fffu + ((v.u >> 16) & 1u)) >> 16;
  return (ushort)r;
}
__device__ __forceinline__ float bf2f(ushort u) {
  union { unsigned u; float f; } v; v.u = ((unsigned)u) << 16;
  return v.f;
}

// ---------------------------------------------------------------------------
// Kernel 0 (merged): blocks 0..19 bf16 twiddle tables; 20..163 projection
// weights -> bf16; 164..931 x (b,n,c) f32 -> xc (b,c,n) bf16 transpose.
// ---------------------------------------------------------------------------
__global__ __launch_bounds__(256) void prep_k(
    ushort* __restrict__ tbl,
    const float* __restrict__ wq, const float* __restrict__ wk,
    const float* __restrict__ wv, const float* __restrict__ wo,
    ushort* __restrict__ wqb, ushort* __restrict__ wkb,
    ushort* __restrict__ wvb, ushort* __restrict__ wob,
    const float* __restrict__ x, ushort* __restrict__ xc)
{
  __shared__ ushort T[128][33];
  if (blockIdx.x < 20) {
    int i = blockIdx.x * 256 + threadIdx.x;
    if (i >= 5 * 1024) return;
    int t = i >> 10, j = i & 1023, r = j >> 5, cidx = j & 31;
    float ang = (float)((r * cidx) & 31) * 0.19634954084936207f;
    float val;
    if (t == 0) val = cosf(ang);
    else if (t == 1) val = sinf(ang);
    else if (t == 2) val = -sinf(ang);
    else {
      if (cidx > 16) val = 0.f;
      else {
        float cv = (cidx == 0 || cidx == 16) ? 1.f : 2.f;
        val = (t == 3) ? cv * cosf(ang) : -cv * sinf(ang);
      }
    }
    tbl[i] = f2bf(val);
  } else if (blockIdx.x < 164) {
    int i = (blockIdx.x - 20) * 256 + threadIdx.x;
    if (i * 4 >= CDIM * CDIM) return;
    float4 va = *(const float4*)&wq[i * 4];
    float4 vb = *(const float4*)&wk[i * 4];
    float4 vc = *(const float4*)&wv[i * 4];
    float4 vd = *(const float4*)&wo[i * 4];
    ushort4 ra = { f2bf(va.x), f2bf(va.y), f2bf(va.z), f2bf(va.w) };
    ushort4 rb = { f2bf(vb.x), f2bf(vb.y), f2bf(vb.z), f2bf(vb.w) };
    ushort4 rc = { f2bf(vc.x), f2bf(vc.y), f2bf(vc.z), f2bf(vc.w) };
    ushort4 rd = { f2bf(vd.x), f2bf(vd.y), f2bf(vd.z), f2bf(vd.w) };
    *(ushort4*)&wqb[i * 4] = ra;
    *(ushort4*)&wkb[i * 4] = rb;
    *(ushort4*)&wvb[i * 4] = rc;
    *(ushort4*)&wob[i * 4] = rd;
  } else {
    int t = blockIdx.x - 164;             // 768 blocks: b*96 + (c0/32)*8 + n0/128
    int b = t / 96, rr = t % 96;
    int c0 = (rr >> 3) * 32, n0 = (rr & 7) * 128;
    for (int i = threadIdx.x; i < 4096; i += 256) {
      int n = i >> 5, c = i & 31;
      T[n][c] = f2bf(x[((long)(b * 1024 + n0 + n)) * CDIM + c0 + c]);
    }
    __syncthreads();
    for (int i = threadIdx.x; i < 4096; i += 256) {
      int c = i >> 7, n = i & 127;
      xc[((long)(b * CDIM + c0 + c)) * 1024 + n0 + n] = T[n][c];
    }
  }
}

// ---------------------------------------------------------------------------
// Kernel 1: spectral filter via MFMA + FUSED depthwise conv3x3 + BN.
// ONE channel per block (exactly 32KB LDS, 5 blocks/CU).
// Conv epilogue: 4 consecutive pixels/thread, col-padded Ysf (no dx bounds),
// shared tap loads, packed ushort4 stores.
// ---------------------------------------------------------------------------
__global__ __launch_bounds__(256) void fft_conv_k(
    const ushort* __restrict__ xc, const float* __restrict__ cw,
    const ushort* __restrict__ tbl,
    const float* __restrict__ dwq, const float* __restrict__ dwk, const float* __restrict__ dwv,
    const float* __restrict__ gq, const float* __restrict__ bq, const float* __restrict__ mq, const float* __restrict__ vq,
    const float* __restrict__ gk, const float* __restrict__ bk, const float* __restrict__ mk, const float* __restrict__ vk,
    const float* __restrict__ gv, const float* __restrict__ bv, const float* __restrict__ mv, const float* __restrict__ vv,
    ushort* __restrict__ yc,
    ushort* __restrict__ qc, ushort* __restrict__ kc, ushort* __restrict__ vc)
{
  const int b = blockIdx.x / CDIM, c = blockIdx.x % CDIM;
  const int tid = threadIdx.x;
  const int w = tid >> 6, lane = tid & 63;
  const int l15 = lane & 15, l16 = lane >> 4;
  __shared__ ushort B[11][32][40];
  __shared__ float YsfP[32][36];        // cols 1..32 = image, col 0/33 zero pad

  float wq9[9], wk9[9], wv9[9];
#pragma unroll
  for (int t = 0; t < 9; ++t) {
    wq9[t] = dwq[c * 9 + t];
    wk9[t] = dwk[c * 9 + t];
    wv9[t] = dwv[c * 9 + t];
  }
  float scq = gq[c] * rsqrtf(vq[c] + 1e-5f); float shq = bq[c] - mq[c] * scq;
  float sck = gk[c] * rsqrtf(vk[c] + 1e-5f); float shk = bk[c] - mk[c] * sck;
  float scv = gv[c] * rsqrtf(vv[c] + 1e-5f); float shv = bv[c] - mv[c] * scv;

  for (int i = tid; i < 640; i += 256) {                 // tables -> LDS
    int t = i >> 7, j = i & 127, r = j >> 2, s = j & 3;
    *(uint4*)&B[t][r][s * 8] = *(const uint4*)&tbl[t * 1024 + r * 32 + s * 8];
  }
  if (tid < 64) {                                        // zero Ysf pad cols
    int r = tid & 31, col = (tid >> 5) ? 33 : 0;
    YsfP[r][col] = 0.f;
  }
  {                                                      // input -> Xt[w][h]
    int i8 = tid * 4;
    ushort4 xv = *(const ushort4*)&xc[(long)(b * CDIM + c) * 1024 + i8];
    int h = i8 >> 5, w0 = i8 & 31;
    B[5][w0 + 0][h] = xv.x; B[5][w0 + 1][h] = xv.y;
    B[5][w0 + 2][h] = xv.z; B[5][w0 + 3][h] = xv.w;
  }
  __syncthreads();

  // stage1: R1[u,w] = sum_h Tc[u,h]*Xt[w,h];  I1 = sum_h Tsn[u,h]*Xt[w,h]
  for (int j = w; j < 8; j += 4) {
    int o = j & 1, ut = (j >> 1) & 1, wt = (j >> 2) & 1;
    short8v af = *(const short8v*)&B[o == 0 ? 0 : 2][ut * 16 + l15][l16 * 8];
    short8v bf = *(const short8v*)&B[5][wt * 16 + l15][l16 * 8];
    float4v acc = {0.f, 0.f, 0.f, 0.f};
    acc = __builtin_amdgcn_mfma_f32_16x16x32_bf16(af, bf, acc, 0, 0, 0);
    int dst = (o == 0) ? 7 : 8;
#pragma unroll
    for (int r = 0; r < 4; ++r)
      B[dst][ut * 16 + l16 * 4 + r][wt * 16 + l15] = f2bf(acc[r]);
  }
  __syncthreads();

  // stage2: Xfr[u,v] = R1.Tc + I1.Ts ; Xfi = I1.Tc + R1.Tsn  (fp32 raw store)
  for (int j = w; j < 8; j += 4) {
    int o = j & 1, ut = (j >> 1) & 1, vt = (j >> 2) & 1;
    short8v a1 = *(const short8v*)&B[o == 0 ? 7 : 8][ut * 16 + l15][l16 * 8];
    short8v b1 = *(const short8v*)&B[0][vt * 16 + l15][l16 * 8];
    short8v a2 = *(const short8v*)&B[o == 0 ? 8 : 7][ut * 16 + l15][l16 * 8];
    short8v b2 = *(const short8v*)&B[o == 0 ? 1 : 2][vt * 16 + l15][l16 * 8];
    float4v acc = {0.f, 0.f, 0.f, 0.f};
    acc = __builtin_amdgcn_mfma_f32_16x16x32_bf16(a1, b1, acc, 0, 0, 0);
    acc = __builtin_amdgcn_mfma_f32_16x16x32_bf16(a2, b2, acc, 0, 0, 0);
    int v = vt * 16 + l15;
    if (v < 17) {
      float* praw = (float*)&B[o == 0 ? 5 : 6][0][0];    // [32][20] f32 view
#pragma unroll
      for (int r = 0; r < 4; ++r)
        praw[(ut * 16 + l16 * 4 + r) * 20 + v] = acc[r];
    }
  }
  __syncthreads();

  // zero Ytr/Yti rows 17..31, then weight-multiply + transpose scatter
  for (int i = tid; i < 150; i += 256) {
    int buf = i / 75, j2 = i % 75, r2 = 17 + j2 / 5, s2 = j2 % 5;
    uint4 z = {0u, 0u, 0u, 0u};
    *(uint4*)&B[9 + buf][r2][s2 * 8] = z;
  }
  {
    const float* xfr = (const float*)&B[5][0][0];
    const float* xfi = (const float*)&B[6][0][0];
    for (int e = tid; e < 544; e += 256) {
      int u = e / 17, v = e - u * 17;
      float fr = xfr[u * 20 + v], fi = xfi[u * 20 + v];
      float2 wc = *(const float2*)&cw[((long)(c * 32 + u) * 17 + v) * 2];
      B[9][v][u]  = f2bf(fr * wc.x - fi * wc.y);
      B[10][v][u] = f2bf(fr * wc.y + fi * wc.x);
    }
  }
  __syncthreads();

  // stage3: Zr[h,v] = Tc(h).Ytr + Tsn(h).Yti ; Zi = Tc(h).Yti + Ts(h).Ytr
  for (int j = w; j < 8; j += 4) {
    int o = j & 1, ht = (j >> 1) & 1, vt = (j >> 2) & 1;
    short8v a1 = *(const short8v*)&B[0][ht * 16 + l15][l16 * 8];
    short8v b1 = *(const short8v*)&B[o == 0 ? 9 : 10][vt * 16 + l15][l16 * 8];
    short8v a2 = *(const short8v*)&B[o == 0 ? 2 : 1][ht * 16 + l15][l16 * 8];
    short8v b2 = *(const short8v*)&B[o == 0 ? 10 : 9][vt * 16 + l15][l16 * 8];
    float4v acc = {0.f, 0.f, 0.f, 0.f};
    acc = __builtin_amdgcn_mfma_f32_16x16x32_bf16(a1, b1, acc, 0, 0, 0);
    acc = __builtin_amdgcn_mfma_f32_16x16x32_bf16(a2, b2, acc, 0, 0, 0);
    int dst = (o == 0) ? 7 : 8;
#pragma unroll
    for (int r = 0; r < 4; ++r)
      B[dst][ht * 16 + l16 * 4 + r][vt * 16 + l15] = f2bf(acc[r]);
  }
  __syncthreads();

  // stage4: y[h,w] = (Zr.Uc^T + Zi.Us^T)/1024 -> YsfP (LDS) + yc (coalesced)
  {
    int ht = w & 1, wt = (w >> 1) & 1;
    short8v a1 = *(const short8v*)&B[7][ht * 16 + l15][l16 * 8];
    short8v b1 = *(const short8v*)&B[3][wt * 16 + l15][l16 * 8];
    short8v a2 = *(const short8v*)&B[8][ht * 16 + l15][l16 * 8];
    short8v b2 = *(const short8v*)&B[4][wt * 16 + l15][l16 * 8];
    float4v acc = {0.f, 0.f, 0.f, 0.f};
    acc = __builtin_amdgcn_mfma_f32_16x16x32_bf16(a1, b1, acc, 0, 0, 0);
    acc = __builtin_amdgcn_mfma_f32_16x16x32_bf16(a2, b2, acc, 0, 0, 0);
#pragma unroll
    for (int r = 0; r < 4; ++r) {
      int hh = ht * 16 + l16 * 4 + r, ww = wt * 16 + l15;
      float y = acc[r] * (1.0f / 1024.0f);
      YsfP[hh][ww + 1] = y;
      yc[(long)(b * CDIM + c) * 1024 + hh * 32 + ww] = f2bf(y);
    }
  }
  __syncthreads();

  // fused depthwise 3x3 conv + BN: 4 consecutive pixels per thread,
  // no dx bounds (col pad), shared tap loads, packed ushort4 stores.
  {
    const int p4 = tid * 4;
    const int hh = p4 >> 5, ww0 = p4 & 31;
    float aq[4] = {0.f, 0.f, 0.f, 0.f};
    float ak[4] = {0.f, 0.f, 0.f, 0.f};
    float av[4] = {0.f, 0.f, 0.f, 0.f};
#pragma unroll
    for (int dy = 0; dy < 3; ++dy) {
      int y0 = hh + dy - 1;
      if (y0 >= 0 && y0 < 32) {
        float4 t0 = *(const float4*)&YsfP[y0][ww0];
        float2 t1 = *(const float2*)&YsfP[y0][ww0 + 4];
        float v[6] = {t0.x, t0.y, t0.z, t0.w, t1.x, t1.y};
#pragma unroll
        for (int j = 0; j < 4; ++j)
#pragma unroll
          for (int dx = 0; dx < 3; ++dx) {
            float xv = v[j + dx];
            int t = dy * 3 + dx;
            aq[j] += xv * wq9[t]; ak[j] += xv * wk9[t]; av[j] += xv * wv9[t];
          }
      }
    }
    long o = (long)(b * CDIM + c) * 1024 + p4;
    ushort4 pq = { f2bf(aq[0] * scq + shq), f2bf(aq[1] * scq + shq),
                   f2bf(aq[2] * scq + shq), f2bf(aq[3] * scq + shq) };
    ushort4 pk = { f2bf(ak[0] * sck + shk), f2bf(ak[1] * sck + shk),
                   f2bf(ak[2] * sck + shk), f2bf(ak[3] * sck + shk) };
    ushort4 pv = { f2bf(av[0] * scv + shv), f2bf(av[1] * scv + shv),
                   f2bf(av[2] * scv + shv), f2bf(av[3] * scv + shv) };
    *(ushort4*)&qc[o] = pq;
    *(ushort4*)&kc[o] = pk;
    *(ushort4*)&vc[o] = pv;
  }
}

// ---------------------------------------------------------------------------
// MFMA GEMM body  C[m,n'] = sum_k A[m,k] W[n',k]
// tile 128x64, BK=64, 4 waves (2x2), padded LDS (stride 72 bf16 = 144B).
// T14-lite software pipeline: global loads for K-step t+1 issued (into
// scalar regs) right after the staging barrier, hidden under compute(t).
// CMA=true: A is c-major (b,c,n); staging does the n<->c transpose in LDS
//   with a row-XOR column swizzle (col ^ (row&56)).
// flags==0: bf16 store (n-major).  flags==1: fp32 write out = acc+bias+y
// (residual from ycr, c-major bf16).  flags==2: bf16 store c-major (ushort4).
// ---------------------------------------------------------------------------
template<bool CMA>
__device__ __forceinline__ void gemm_body(
    const ushort* __restrict__ A, const ushort* __restrict__ Wb,
    const float* __restrict__ bias, const ushort* __restrict__ ycr,
    void* __restrict__ Cd, int flags, int bx, int by)
{
  __shared__ ushort As[128][72];
  __shared__ ushort Ws[64][72];
  const int tid = threadIdx.x;
  const int w = tid >> 6, lane = tid & 63;
  const int l15 = lane & 15, l16 = lane >> 4;
  const int wm = w >> 1, wn = w & 1;
  const int row0 = bx * 128, col0 = by * 64;
  const int btok = row0 >> 10;           // batch index
  const int ntok0 = row0 & 1023;
  const int ra = tid >> 3, sa8 = (tid & 7) * 8;   // staging coords
  const int g = tid & 15, u4 = (tid >> 4) * 4;     // CMA staging coords
  const int colu = u4 ^ ((g & 7) << 3);
  float4v acc[4][2];
#pragma unroll
  for (int i = 0; i < 4; ++i)
#pragma unroll
    for (int j = 0; j < 2; ++j) acc[i][j] = (float4v){0.f, 0.f, 0.f, 0.f};

  uint4 a0, a1, a2, a3, w0, w1;
#define GLOAD(KT) do { \
    if (CMA) { \
      const long ab = ((long)(btok * CDIM + (KT) + u4)) * 1024 + ntok0 + g * 8; \
      a0 = *(const uint4*)&A[ab + 0 * 1024]; \
      a1 = *(const uint4*)&A[ab + 1 * 1024]; \
      a2 = *(const uint4*)&A[ab + 2 * 1024]; \
      a3 = *(const uint4*)&A[ab + 3 * 1024]; \
    } else { \
      const long ab = (long)(row0 + ra) * CDIM + (KT) + sa8; \
      a0 = *(const uint4*)&A[ab + (long)0 * 32 * CDIM]; \
      a1 = *(const uint4*)&A[ab + (long)1 * 32 * CDIM]; \
      a2 = *(const uint4*)&A[ab + (long)2 * 32 * CDIM]; \
      a3 = *(const uint4*)&A[ab + (long)3 * 32 * CDIM]; \
    } \
    const long wb = (long)(col0 + ra) * CDIM + (KT) + sa8; \
    w0 = *(const uint4*)&Wb[wb]; \
    w1 = *(const uint4*)&Wb[wb + (long)32 * CDIM]; } while (0)

#define LWRITE() do { \
    if (CMA) { \
      const ushort* s0 = (const ushort*)&a0; \
      const ushort* s1 = (const ushort*)&a1; \
      const ushort* s2 = (const ushort*)&a2; \
      const ushort* s3 = (const ushort*)&a3; \
      _Pragma("unroll") \
      for (int i = 0; i < 8; ++i) { \
        uint2 wv; \
        wv.x = (unsigned)s0[i] | ((unsigned)s1[i] << 16); \
        wv.y = (unsigned)s2[i] | ((unsigned)s3[i] << 16); \
        *(uint2*)&As[g * 8 + i][colu] = wv; \
      } \
    } else { \
      *(uint4*)&As[ra +  0][sa8] = a0; \
      *(uint4*)&As[ra + 32][sa8] = a1; \
      *(uint4*)&As[ra + 64][sa8] = a2; \
      *(uint4*)&As[ra + 96][sa8] = a3; \
    } \
    *(uint4*)&Ws[ra][sa8] = w0; \
    *(uint4*)&Ws[ra + 32][sa8] = w1; } while (0)

  GLOAD(0);
  for (int kt = 0; kt < CDIM; kt += 64) {
    LWRITE();
    __syncthreads();
    if (kt + 64 < CDIM) GLOAD(kt + 64);  // hidden under compute
#pragma unroll
    for (int s = 0; s < 2; ++s) {
      short8v a[4], bfr[2];
#pragma unroll
      for (int i = 0; i < 4; ++i) {
        int arow = wm * 64 + i * 16 + l15;
        int acol = s * 32 + l16 * 8;
        if (CMA) acol ^= (arow & 56);
        a[i] = *(const short8v*)&As[arow][acol];
      }
#pragma unroll
      for (int j = 0; j < 2; ++j)
        bfr[j] = *(const short8v*)&Ws[wn * 32 + j * 16 + l15][s * 32 + l16 * 8];
#pragma unroll
      for (int i = 0; i < 4; ++i)
#pragma unroll
        for (int j = 0; j < 2; ++j)
          acc[i][j] = __builtin_amdgcn_mfma_f32_16x16x32_bf16(a[i], bfr[j], acc[i][j], 0, 0, 0);
    }
    if (kt + 64 < CDIM) __syncthreads();
  }
#undef GLOAD
#undef LWRITE
#pragma unroll
  for (int i = 0; i < 4; ++i)
#pragma unroll
    for (int j = 0; j < 2; ++j) {
      int col = col0 + wn * 32 + j * 16 + l15;
      int rbase = row0 + wm * 64 + i * 16 + l16 * 4;
      int ntok = ntok0 + wm * 64 + i * 16 + l16 * 4;
      if (flags == 2) {
        ushort4 pk = { f2bf(acc[i][j][0]), f2bf(acc[i][j][1]),
                       f2bf(acc[i][j][2]), f2bf(acc[i][j][3]) };
        *(ushort4*)&((ushort*)Cd)[((long)(btok * CDIM + col)) * 1024 + ntok] = pk;
      } else if (flags == 1) {
        ushort4 yv = *(const ushort4*)&ycr[((long)(btok * CDIM + col)) * 1024 + ntok];
        float bcol = bias[col];
        float* op = (float*)Cd;
        op[(long)(rbase + 0) * CDIM + col] = acc[i][j][0] + bcol + bf2f(yv.x);
        op[(long)(rbase + 1) * CDIM + col] = acc[i][j][1] + bcol + bf2f(yv.y);
        op[(long)(rbase + 2) * CDIM + col] = acc[i][j][2] + bcol + bf2f(yv.z);
        op[(long)(rbase + 3) * CDIM + col] = acc[i][j][3] + bcol + bf2f(yv.w);
      } else {
#pragma unroll
        for (int r = 0; r < 4; ++r)
          ((ushort*)Cd)[(long)(rbase + r) * CDIM + col] = f2bf(acc[i][j][r]);
      }
    }
}

// fused q/k/v projection GEMMs reading c-major conv outputs directly.
// z==2 (V) writes its output c-major.
__global__ __launch_bounds__(256) void gemm_qkv_k(
    const ushort* __restrict__ qc, const ushort* __restrict__ kc, const ushort* __restrict__ vc,
    const ushort* __restrict__ wqb, const ushort* __restrict__ wkb, const ushort* __restrict__ wvb,
    ushort* __restrict__ q1, ushort* __restrict__ k1, ushort* __restrict__ vtc)
{
  const int z = blockIdx.z;
  const ushort* A  = z == 0 ? qc  : z == 1 ? kc  : vc;
  const ushort* Wb = z == 0 ? wqb : z == 1 ? wkb : wvb;
  ushort*       C  = z == 0 ? q1  : z == 1 ? k1  : vtc;
  gemm_body<true>(A, Wb, nullptr, nullptr, C, z == 2 ? 2 : 0, blockIdx.x, blockIdx.y);
}

// final projection: out = A@wo^T + bo + x_fft (residual from yc)
__global__ __launch_bounds__(256) void gemm_out_k(
    const ushort* __restrict__ A, const ushort* __restrict__ Wb,
    const float* __restrict__ bias, const ushort* __restrict__ ycr,
    float* __restrict__ Cd)
{
  gemm_body<false>(A, Wb, bias, ycr, Cd, 1, blockIdx.x, blockIdx.y);
}

// ---------------------------------------------------------------------------
// Kernel 4: MFMA flash attention, TWO 64-row q-tiles per block (grid 64x8).
// K/V staging + barriers shared by 2x compute.  Swapped QK^T, cvt_pk P pack,
// no-max softmax, ones-MFMA row sums, Q direct from global, T14-lite reg
// prefetch of the next K/V tile.
// ---------------------------------------------------------------------------
__global__ __launch_bounds__(256) void attn_mfma_k(
    const ushort* __restrict__ q1, const ushort* __restrict__ k1,
    const ushort* __restrict__ vt, ushort* __restrict__ ao)
{
  const int bh = blockIdx.x, qt2 = blockIdx.y;
  const int b = bh >> 3, h = bh & 7;
  const int tid = threadIdx.x;
  const int w = tid >> 6, lane = tid & 63;
  const int l15 = lane & 15, l16 = lane >> 4;
  __shared__ ushort Ks[64][72], Vs[48][72], Ps[128][72];
  const float scale = 0.051031036307982884f;  // 384^-0.5
  const long base = (long)b * NPIX * CDIM + h * 48;
  const long vbase = (long)bh * 48 * NPIX;

  // per-thread staging descriptors (scalars -> no scratch).
  const int i0 = tid, i1 = tid + 256, i2 = tid + 512;
  const int r0 = i0 / 6, s0 = i0 - r0 * 6;
  const ushort* gp0 = k1 + base + (long)r0 * CDIM + s0 * 8;
  const long st0 = (long)64 * CDIM;
  ushort* lp0 = &Ks[r0][s0 * 8];
  const ushort* gp1; long st1; ushort* lp1;
  if (i1 < 384) {
    int r = i1 / 6, s = i1 - r * 6;
    gp1 = k1 + base + (long)r * CDIM + s * 8; st1 = (long)64 * CDIM; lp1 = &Ks[r][s * 8];
  } else {
    int j = i1 - 384, d = j >> 3, s = j & 7;
    gp1 = vt + vbase + (long)d * NPIX + s * 8; st1 = 64; lp1 = &Vs[d][s * 8];
  }
  const int j2 = i2 - 384, d2 = j2 >> 3, s2 = j2 & 7;
  const ushort* gp2 = vt + vbase + (long)d2 * NPIX + s2 * 8;
  const long st2 = 64;
  ushort* lp2 = &Vs[d2][s2 * 8];

  // zero K pad (cols 48..63), persists across iterations
  if (tid < 128) {
    uint4 z4 = {0u, 0u, 0u, 0u};
    int r = tid >> 1, s = tid & 1;
    *(uint4*)&Ks[r][48 + s * 8] = z4;
  }
  // Q fragments for both q-tile halves, direct from global
  const long qrowA = base + (long)(qt2 * 128 + w * 16 + l15) * CDIM;
  const long qrowB = qrowA + (long)64 * CDIM;
  short8v qa0A = *(const short8v*)&q1[qrowA + l16 * 8];
  short8v qa0B = *(const short8v*)&q1[qrowB + l16 * 8];
  short8v qa1A, qa1B;
  {
    short8v qz = {};
    short8v qvA = *(const short8v*)&q1[qrowA + ((l16 < 2) ? 32 + l16 * 8 : 0)];
    short8v qvB = *(const short8v*)&q1[qrowB + ((l16 < 2) ? 32 + l16 * 8 : 0)];
    qa1A = (l16 < 2) ? qvA : qz;
    qa1B = (l16 < 2) ? qvB : qz;
  }

  float lrunA[4] = {0.f, 0.f, 0.f, 0.f}, lrunB[4] = {0.f, 0.f, 0.f, 0.f};
  float4v accOA[3], accOB[3];
#pragma unroll
  for (int fd = 0; fd < 3; ++fd) {
    accOA[fd] = (float4v){0.f, 0.f, 0.f, 0.f};
    accOB[fd] = (float4v){0.f, 0.f, 0.f, 0.f};
  }
  short8v onesb;
#pragma unroll
  for (int j = 0; j < 8; ++j) onesb[j] = (short)0x3F80;  // bf16 1.0

  uint4 t0 = *(const uint4*)gp0;          // tile 0 loads
  uint4 t1 = *(const uint4*)gp1;
  uint4 t2 = *(const uint4*)gp2;

  for (int kt = 0; kt < 16; ++kt) {
    *(uint4*)lp0 = t0;
    *(uint4*)lp1 = t1;
    *(uint4*)lp2 = t2;
    __syncthreads();
    if (kt + 1 < 16) {                    // issue loads for t+1 under compute
      t0 = *(const uint4*)(gp0 + (long)(kt + 1) * st0);
      t1 = *(const uint4*)(gp1 + (long)(kt + 1) * st1);
      t2 = *(const uint4*)(gp2 + (long)(kt + 1) * st2);
    }
    // swapped QK^T for both halves: K frags loaded once
    float4v saccA[4], saccB[4];
#pragma unroll
    for (int fc = 0; fc < 4; ++fc) {
      short8v kb0 = *(const short8v*)&Ks[fc * 16 + l15][l16 * 8];
      short8v kb1 = *(const short8v*)&Ks[fc * 16 + l15][32 + l16 * 8];
      saccA[fc] = (float4v){0.f, 0.f, 0.f, 0.f};
      saccA[fc] = __builtin_amdgcn_mfma_f32_16x16x32_bf16(kb0, qa0A, saccA[fc], 0, 0, 0);
      saccA[fc] = __builtin_amdgcn_mfma_f32_16x16x32_bf16(kb1, qa1A, saccA[fc], 0, 0, 0);
      saccB[fc] = (float4v){0.f, 0.f, 0.f, 0.f};
      saccB[fc] = __builtin_amdgcn_mfma_f32_16x16x32_bf16(kb0, qa0B, saccB[fc], 0, 0, 0);
      saccB[fc] = __builtin_amdgcn_mfma_f32_16x16x32_bf16(kb1, qa1B, saccB[fc], 0, 0, 0);
    }
    // P = exp(S*scale); pack pairs -> dword stores (rows wave-private)
    unsigned* prowA = (unsigned*)&Ps[w * 16 + l15][0];
    unsigned* prowB = (unsigned*)&Ps[64 + w * 16 + l15][0];
#pragma unroll
    for (int fc = 0; fc < 4; ++fc) {
      float a0f = __expf(saccA[fc][0] * scale), a1f = __expf(saccA[fc][1] * scale);
      float a2f = __expf(saccA[fc][2] * scale), a3f = __expf(saccA[fc][3] * scale);
      __hip_bfloat162 dA01 = __float22bfloat162_rn(make_float2(a0f, a1f));
      __hip_bfloat162 dA23 = __float22bfloat162_rn(make_float2(a2f, a3f));
      prowA[fc * 8 + l16 * 2 + 0] = *(unsigned*)&dA01;
      prowA[fc * 8 + l16 * 2 + 1] = *(unsigned*)&dA23;
      float b0f = __expf(saccB[fc][0] * scale), b1f = __expf(saccB[fc][1] * scale);
      float b2f = __expf(saccB[fc][2] * scale), b3f = __expf(saccB[fc][3] * scale);
      __hip_bfloat162 dB01 = __float22bfloat162_rn(make_float2(b0f, b1f));
      __hip_bfloat162 dB23 = __float22bfloat162_rn(make_float2(b2f, b3f));
      prowB[fc * 8 + l16 * 2 + 0] = *(unsigned*)&dB01;
      prowB[fc * 8 + l16 * 2 + 1] = *(unsigned*)&dB23;
    }
    asm volatile("s_waitcnt lgkmcnt(0)" ::: "memory");
    __builtin_amdgcn_sched_barrier(0);
    short8v pa0A = *(const short8v*)&Ps[w * 16 + l15][l16 * 8];
    short8v pa1A = *(const short8v*)&Ps[w * 16 + l15][32 + l16 * 8];
    short8v pa0B = *(const short8v*)&Ps[64 + w * 16 + l15][l16 * 8];
    short8v pa1B = *(const short8v*)&Ps[64 + w * 16 + l15][32 + l16 * 8];
    // row sums via ones-MFMA
    float4v srA = (float4v){0.f, 0.f, 0.f, 0.f};
    srA = __builtin_amdgcn_mfma_f32_16x16x32_bf16(pa0A, onesb, srA, 0, 0, 0);
    srA = __builtin_amdgcn_mfma_f32_16x16x32_bf16(pa1A, onesb, srA, 0, 0, 0);
    float4v srB = (float4v){0.f, 0.f, 0.f, 0.f};
    srB = __builtin_amdgcn_mfma_f32_16x16x32_bf16(pa0B, onesb, srB, 0, 0, 0);
    srB = __builtin_amdgcn_mfma_f32_16x16x32_bf16(pa1B, onesb, srB, 0, 0, 0);
#pragma unroll
    for (int r = 0; r < 4; ++r) { lrunA[r] += srA[r]; lrunB[r] += srB[r]; }
    // PV for both halves; V frags loaded once
#pragma unroll
    for (int fd = 0; fd < 3; ++fd) {
      short8v vb0 = *(const short8v*)&Vs[fd * 16 + l15][l16 * 8];
      short8v vb1 = *(const short8v*)&Vs[fd * 16 + l15][32 + l16 * 8];
      accOA[fd] = __builtin_amdgcn_mfma_f32_16x16x32_bf16(pa0A, vb0, accOA[fd], 0, 0, 0);
      accOA[fd] = __builtin_amdgcn_mfma_f32_16x16x32_bf16(pa1A, vb1, accOA[fd], 0, 0, 0);
      accOB[fd] = __builtin_amdgcn_mfma_f32_16x16x32_bf16(pa0B, vb0, accOB[fd], 0, 0, 0);
      accOB[fd] = __builtin_amdgcn_mfma_f32_16x16x32_bf16(pa1B, vb1, accOB[fd], 0, 0, 0);
    }
    __syncthreads();                      // compute done; LDS free for t+1
  }
  float invA[4], invB[4];
#pragma unroll
  for (int r = 0; r < 4; ++r) { invA[r] = 1.f / lrunA[r]; invB[r] = 1.f / lrunB[r]; }
#pragma unroll
  for (int fd = 0; fd < 3; ++fd)
#pragma unroll
    for (int r = 0; r < 4; ++r) {
      int qrA = qt2 * 128 + w * 16 + l16 * 4 + r;
      ao[base + (long)qrA * CDIM + fd * 16 + l15] = f2bf(accOA[fd][r] * invA[r]);
      ao[base + (long)(qrA + 64) * CDIM + fd * 16 + l15] = f2bf(accOB[fd][r] * invB[r]);
    }
}

// ---------------------------------------------------------------------------
extern "C" void kernel_launch(void* const* d_in, const int* in_sizes, int n_in,
                              void* d_out, int out_size, void* d_ws, size_t ws_size,
                              hipStream_t stream) {
  const float* x   = (const float*)d_in[0];
  const float* cw  = (const float*)d_in[1];
  const float* dwq = (const float*)d_in[2];
  const float* dwk = (const float*)d_in[3];
  const float* dwv = (const float*)d_in[4];
  const float* gq  = (const float*)d_in[5];
  const float* bq  = (const float*)d_in[6];
  const float* mq  = (const float*)d_in[7];
  const float* vq  = (const float*)d_in[8];
  const float* gk  = (const float*)d_in[9];
  const float* bk  = (const float*)d_in[10];
  const float* mk  = (const float*)d_in[11];
  const float* vk  = (const float*)d_in[12];
  const float* gv  = (const float*)d_in[13];
  const float* bv  = (const float*)d_in[14];
  const float* mv  = (const float*)d_in[15];
  const float* vv  = (const float*)d_in[16];
  const float* wq  = (const float*)d_in[17];
  const float* wk  = (const float*)d_in[18];
  const float* wv  = (const float*)d_in[19];
  const float* wo  = (const float*)d_in[20];
  const float* bo  = (const float*)d_in[21];
  float* out = (float*)d_out;

  char* wsb = (char*)d_ws;
  const size_t H = (size_t)NB * NPIX * CDIM * 2;        // 6,291,456 B
  // slot plan (each H):
  // S0: xc -> vtc | S1: yc | S2: qc -> ao | S3: kc | S4: vc
  // S5: q1 | S6: k1 | S7: weights + tbl
  ushort* xcp = (ushort*)(wsb + 0 * H);
  ushort* vtc = (ushort*)(wsb + 0 * H);
  ushort* yc  = (ushort*)(wsb + 1 * H);
  ushort* qc  = (ushort*)(wsb + 2 * H);
  ushort* ao  = (ushort*)(wsb + 2 * H);
  ushort* kc  = (ushort*)(wsb + 3 * H);
  ushort* vc  = (ushort*)(wsb + 4 * H);
  ushort* q1  = (ushort*)(wsb + 5 * H);
  ushort* k1  = (ushort*)(wsb + 6 * H);
  ushort* wqb = (ushort*)(wsb + 7 * H);
  ushort* wkb = wqb + CDIM * CDIM;
  ushort* wvb = wkb + CDIM * CDIM;
  ushort* wob = wvb + CDIM * CDIM;
  ushort* tbl = wob + CDIM * CDIM;                      // 5*1024 ushorts

  prep_k<<<dim3(932), 256, 0, stream>>>(tbl, wq, wk, wv, wo,
      wqb, wkb, wvb, wob, x, xcp);
  fft_conv_k<<<dim3(NB * CDIM), 256, 0, stream>>>(xcp, cw, tbl, dwq, dwk, dwv,
      gq, bq, mq, vq, gk, bk, mk, vk, gv, bv, mv, vv, yc, qc, kc, vc);
  gemm_qkv_k<<<dim3(64, 6, 3), 256, 0, stream>>>(qc, kc, vc, wqb, wkb, wvb, q1, k1, vtc);
  attn_mfma_k<<<dim3(64, 8), 256, 0, stream>>>(q1, k1, vtc, ao);
  gemm_out_k<<<dim3(64, 6), 256, 0, stream>>>(ao, wob, bo, yc, out);
}

// Round 18
// 85.503 us; speedup vs baseline: 1.3124x; 1.0310x over previous
//
#include <hip/hip_runtime.h>
#include <hip/hip_bf16.h>
#include <cmath>

#define CDIM 384
#define NB 8
#define NPIX 1024

typedef __attribute__((ext_vector_type(8))) short short8v;
typedef __attribute__((ext_vector_type(4))) float float4v;

__device__ __forceinline__ ushort f2bf(float f) {
  union { float f; unsigned u; } v; v.f = f;
  unsigned r = (v.u + 0x7fffu + ((v.u >> 16) & 1u)) >> 16;
  return (ushort)r;
}
__device__ __forceinline__ float bf2f(ushort u) {
  union { unsigned u; float f; } v; v.u = ((unsigned)u) << 16;
  return v.f;
}

// ---------------------------------------------------------------------------
// Kernel 0 (merged): blocks 0..19 bf16 twiddle tables; 20..163 projection
// weights -> bf16; 164..931 x (b,n,c) f32 -> xc (b,c,n) bf16 transpose.
// ---------------------------------------------------------------------------
__global__ __launch_bounds__(256) void prep_k(
    ushort* __restrict__ tbl,
    const float* __restrict__ wq, const float* __restrict__ wk,
    const float* __restrict__ wv, const float* __restrict__ wo,
    ushort* __restrict__ wqb, ushort* __restrict__ wkb,
    ushort* __restrict__ wvb, ushort* __restrict__ wob,
    const float* __restrict__ x, ushort* __restrict__ xc)
{
  __shared__ ushort T[128][33];
  if (blockIdx.x < 20) {
    int i = blockIdx.x * 256 + threadIdx.x;
    if (i >= 5 * 1024) return;
    int t = i >> 10, j = i & 1023, r = j >> 5, cidx = j & 31;
    float ang = (float)((r * cidx) & 31) * 0.19634954084936207f;
    float val;
    if (t == 0) val = cosf(ang);
    else if (t == 1) val = sinf(ang);
    else if (t == 2) val = -sinf(ang);
    else {
      if (cidx > 16) val = 0.f;
      else {
        float cv = (cidx == 0 || cidx == 16) ? 1.f : 2.f;
        val = (t == 3) ? cv * cosf(ang) : -cv * sinf(ang);
      }
    }
    tbl[i] = f2bf(val);
  } else if (blockIdx.x < 164) {
    int i = (blockIdx.x - 20) * 256 + threadIdx.x;
    if (i * 4 >= CDIM * CDIM) return;
    float4 va = *(const float4*)&wq[i * 4];
    float4 vb = *(const float4*)&wk[i * 4];
    float4 vc = *(const float4*)&wv[i * 4];
    float4 vd = *(const float4*)&wo[i * 4];
    ushort4 ra = { f2bf(va.x), f2bf(va.y), f2bf(va.z), f2bf(va.w) };
    ushort4 rb = { f2bf(vb.x), f2bf(vb.y), f2bf(vb.z), f2bf(vb.w) };
    ushort4 rc = { f2bf(vc.x), f2bf(vc.y), f2bf(vc.z), f2bf(vc.w) };
    ushort4 rd = { f2bf(vd.x), f2bf(vd.y), f2bf(vd.z), f2bf(vd.w) };
    *(ushort4*)&wqb[i * 4] = ra;
    *(ushort4*)&wkb[i * 4] = rb;
    *(ushort4*)&wvb[i * 4] = rc;
    *(ushort4*)&wob[i * 4] = rd;
  } else {
    int t = blockIdx.x - 164;             // 768 blocks: b*96 + (c0/32)*8 + n0/128
    int b = t / 96, rr = t % 96;
    int c0 = (rr >> 3) * 32, n0 = (rr & 7) * 128;
    for (int i = threadIdx.x; i < 4096; i += 256) {
      int n = i >> 5, c = i & 31;
      T[n][c] = f2bf(x[((long)(b * 1024 + n0 + n)) * CDIM + c0 + c]);
    }
    __syncthreads();
    for (int i = threadIdx.x; i < 4096; i += 256) {
      int c = i >> 7, n = i & 127;
      xc[((long)(b * CDIM + c0 + c)) * 1024 + n0 + n] = T[n][c];
    }
  }
}

// ---------------------------------------------------------------------------
// Kernel 1: spectral filter via MFMA + FUSED depthwise conv3x3 + BN.
// ONE channel per block (32KB LDS).  Stage 2 computes BOTH Xfr and Xfi in a
// single job (4 MFMAs) so the complex-weight multiply happens in-register and
// writes Ytr/Yti directly — one fewer barrier, no fp32 Xf round-trip.
// Ytr/Yti rows 17..31 zeroed in the prologue.
// ---------------------------------------------------------------------------
__global__ __launch_bounds__(256) void fft_conv_k(
    const ushort* __restrict__ xc, const float* __restrict__ cw,
    const ushort* __restrict__ tbl,
    const float* __restrict__ dwq, const float* __restrict__ dwk, const float* __restrict__ dwv,
    const float* __restrict__ gq, const float* __restrict__ bq, const float* __restrict__ mq, const float* __restrict__ vq,
    const float* __restrict__ gk, const float* __restrict__ bk, const float* __restrict__ mk, const float* __restrict__ vk,
    const float* __restrict__ gv, const float* __restrict__ bv, const float* __restrict__ mv, const float* __restrict__ vv,
    ushort* __restrict__ yc,
    ushort* __restrict__ qc, ushort* __restrict__ kc, ushort* __restrict__ vc)
{
  const int b = blockIdx.x / CDIM, c = blockIdx.x % CDIM;
  const int tid = threadIdx.x;
  const int w = tid >> 6, lane = tid & 63;
  const int l15 = lane & 15, l16 = lane >> 4;
  __shared__ ushort B[11][32][40];
  __shared__ float YsfP[32][36];        // cols 1..32 = image, col 0/33 zero pad

  float wq9[9], wk9[9], wv9[9];
#pragma unroll
  for (int t = 0; t < 9; ++t) {
    wq9[t] = dwq[c * 9 + t];
    wk9[t] = dwk[c * 9 + t];
    wv9[t] = dwv[c * 9 + t];
  }
  float scq = gq[c] * rsqrtf(vq[c] + 1e-5f); float shq = bq[c] - mq[c] * scq;
  float sck = gk[c] * rsqrtf(vk[c] + 1e-5f); float shk = bk[c] - mk[c] * sck;
  float scv = gv[c] * rsqrtf(vv[c] + 1e-5f); float shv = bv[c] - mv[c] * scv;

  for (int i = tid; i < 640; i += 256) {                 // tables -> LDS
    int t = i >> 7, j = i & 127, r = j >> 2, s = j & 3;
    *(uint4*)&B[t][r][s * 8] = *(const uint4*)&tbl[t * 1024 + r * 32 + s * 8];
  }
  for (int i = tid; i < 150; i += 256) {                 // zero Ytr/Yti rows 17..31
    int buf = i / 75, j2 = i % 75, r2 = 17 + j2 / 5, s2 = j2 % 5;
    uint4 z = {0u, 0u, 0u, 0u};
    *(uint4*)&B[9 + buf][r2][s2 * 8] = z;
  }
  if (tid < 64) {                                        // zero Ysf pad cols
    int r = tid & 31, col = (tid >> 5) ? 33 : 0;
    YsfP[r][col] = 0.f;
  }
  {                                                      // input -> Xt[w][h]
    int i8 = tid * 4;
    ushort4 xv = *(const ushort4*)&xc[(long)(b * CDIM + c) * 1024 + i8];
    int h = i8 >> 5, w0 = i8 & 31;
    B[5][w0 + 0][h] = xv.x; B[5][w0 + 1][h] = xv.y;
    B[5][w0 + 2][h] = xv.z; B[5][w0 + 3][h] = xv.w;
  }
  __syncthreads();

  // stage1: R1[u,w] = sum_h Tc[u,h]*Xt[w,h];  I1 = sum_h Tsn[u,h]*Xt[w,h]
  for (int j = w; j < 8; j += 4) {
    int o = j & 1, ut = (j >> 1) & 1, wt = (j >> 2) & 1;
    short8v af = *(const short8v*)&B[o == 0 ? 0 : 2][ut * 16 + l15][l16 * 8];
    short8v bf = *(const short8v*)&B[5][wt * 16 + l15][l16 * 8];
    float4v acc = {0.f, 0.f, 0.f, 0.f};
    acc = __builtin_amdgcn_mfma_f32_16x16x32_bf16(af, bf, acc, 0, 0, 0);
    int dst = (o == 0) ? 7 : 8;
#pragma unroll
    for (int r = 0; r < 4; ++r)
      B[dst][ut * 16 + l16 * 4 + r][wt * 16 + l15] = f2bf(acc[r]);
  }
  __syncthreads();

  // stage2 (merged): one job per wave computes BOTH
  //   Xfr = R1.Tc + I1.Ts   and   Xfi = I1.Tc + R1.Tsn
  // for quadrant (ut, vt), then applies the complex weight in-register and
  // scatters Ytr/Yti transposed.  16 MFMAs total, no fp32 round-trip.
  {
    int ut = w & 1, vt = (w >> 1) & 1;
    short8v aR = *(const short8v*)&B[7][ut * 16 + l15][l16 * 8];
    short8v aI = *(const short8v*)&B[8][ut * 16 + l15][l16 * 8];
    short8v bC  = *(const short8v*)&B[0][vt * 16 + l15][l16 * 8];
    short8v bS  = *(const short8v*)&B[1][vt * 16 + l15][l16 * 8];
    short8v bSn = *(const short8v*)&B[2][vt * 16 + l15][l16 * 8];
    float4v accR = {0.f, 0.f, 0.f, 0.f};
    float4v accI = {0.f, 0.f, 0.f, 0.f};
    accR = __builtin_amdgcn_mfma_f32_16x16x32_bf16(aR, bC, accR, 0, 0, 0);
    accR = __builtin_amdgcn_mfma_f32_16x16x32_bf16(aI, bS, accR, 0, 0, 0);
    accI = __builtin_amdgcn_mfma_f32_16x16x32_bf16(aI, bC, accI, 0, 0, 0);
    accI = __builtin_amdgcn_mfma_f32_16x16x32_bf16(aR, bSn, accI, 0, 0, 0);
    int v = vt * 16 + l15;
    if (v < 17) {
#pragma unroll
      for (int r = 0; r < 4; ++r) {
        int u = ut * 16 + l16 * 4 + r;
        float2 wc = *(const float2*)&cw[((long)(c * 32 + u) * 17 + v) * 2];
        float fr = accR[r], fi = accI[r];
        B[9][v][u]  = f2bf(fr * wc.x - fi * wc.y);
        B[10][v][u] = f2bf(fr * wc.y + fi * wc.x);
      }
    }
  }
  __syncthreads();

  // stage3: Zr[h,v] = Tc(h).Ytr + Tsn(h).Yti ; Zi = Tc(h).Yti + Ts(h).Ytr
  for (int j = w; j < 8; j += 4) {
    int o = j & 1, ht = (j >> 1) & 1, vt = (j >> 2) & 1;
    short8v a1 = *(const short8v*)&B[0][ht * 16 + l15][l16 * 8];
    short8v b1 = *(const short8v*)&B[o == 0 ? 9 : 10][vt * 16 + l15][l16 * 8];
    short8v a2 = *(const short8v*)&B[o == 0 ? 2 : 1][ht * 16 + l15][l16 * 8];
    short8v b2 = *(const short8v*)&B[o == 0 ? 10 : 9][vt * 16 + l15][l16 * 8];
    float4v acc = {0.f, 0.f, 0.f, 0.f};
    acc = __builtin_amdgcn_mfma_f32_16x16x32_bf16(a1, b1, acc, 0, 0, 0);
    acc = __builtin_amdgcn_mfma_f32_16x16x32_bf16(a2, b2, acc, 0, 0, 0);
    int dst = (o == 0) ? 7 : 8;
#pragma unroll
    for (int r = 0; r < 4; ++r)
      B[dst][ht * 16 + l16 * 4 + r][vt * 16 + l15] = f2bf(acc[r]);
  }
  __syncthreads();

  // stage4: y[h,w] = (Zr.Uc^T + Zi.Us^T)/1024 -> YsfP (LDS) + yc (coalesced)
  {
    int ht = w & 1, wt = (w >> 1) & 1;
    short8v a1 = *(const short8v*)&B[7][ht * 16 + l15][l16 * 8];
    short8v b1 = *(const short8v*)&B[3][wt * 16 + l15][l16 * 8];
    short8v a2 = *(const short8v*)&B[8][ht * 16 + l15][l16 * 8];
    short8v b2 = *(const short8v*)&B[4][wt * 16 + l15][l16 * 8];
    float4v acc = {0.f, 0.f, 0.f, 0.f};
    acc = __builtin_amdgcn_mfma_f32_16x16x32_bf16(a1, b1, acc, 0, 0, 0);
    acc = __builtin_amdgcn_mfma_f32_16x16x32_bf16(a2, b2, acc, 0, 0, 0);
#pragma unroll
    for (int r = 0; r < 4; ++r) {
      int hh = ht * 16 + l16 * 4 + r, ww = wt * 16 + l15;
      float y = acc[r] * (1.0f / 1024.0f);
      YsfP[hh][ww + 1] = y;
      yc[(long)(b * CDIM + c) * 1024 + hh * 32 + ww] = f2bf(y);
    }
  }
  __syncthreads();

  // fused depthwise 3x3 conv + BN: 4 consecutive pixels per thread,
  // no dx bounds (col pad), shared tap loads, packed ushort4 stores.
  {
    const int p4 = tid * 4;
    const int hh = p4 >> 5, ww0 = p4 & 31;
    float aq[4] = {0.f, 0.f, 0.f, 0.f};
    float ak[4] = {0.f, 0.f, 0.f, 0.f};
    float av[4] = {0.f, 0.f, 0.f, 0.f};
#pragma unroll
    for (int dy = 0; dy < 3; ++dy) {
      int y0 = hh + dy - 1;
      if (y0 >= 0 && y0 < 32) {
        float4 t0 = *(const float4*)&YsfP[y0][ww0];
        float2 t1 = *(const float2*)&YsfP[y0][ww0 + 4];
        float v[6] = {t0.x, t0.y, t0.z, t0.w, t1.x, t1.y};
#pragma unroll
        for (int j = 0; j < 4; ++j)
#pragma unroll
          for (int dx = 0; dx < 3; ++dx) {
            float xv = v[j + dx];
            int t = dy * 3 + dx;
            aq[j] += xv * wq9[t]; ak[j] += xv * wk9[t]; av[j] += xv * wv9[t];
          }
      }
    }
    long o = (long)(b * CDIM + c) * 1024 + p4;
    ushort4 pq = { f2bf(aq[0] * scq + shq), f2bf(aq[1] * scq + shq),
                   f2bf(aq[2] * scq + shq), f2bf(aq[3] * scq + shq) };
    ushort4 pk = { f2bf(ak[0] * sck + shk), f2bf(ak[1] * sck + shk),
                   f2bf(ak[2] * sck + shk), f2bf(ak[3] * sck + shk) };
    ushort4 pv = { f2bf(av[0] * scv + shv), f2bf(av[1] * scv + shv),
                   f2bf(av[2] * scv + shv), f2bf(av[3] * scv + shv) };
    *(ushort4*)&qc[o] = pq;
    *(ushort4*)&kc[o] = pk;
    *(ushort4*)&vc[o] = pv;
  }
}

// ---------------------------------------------------------------------------
// MFMA GEMM body  C[m,n'] = sum_k A[m,k] W[n',k]
// tile 128x64, BK=64, 4 waves (2x2), padded LDS (stride 72 bf16 = 144B).
// T14-lite software pipeline: global loads for K-step t+1 issued (into
// scalar regs) right after the staging barrier, hidden under compute(t).
// CMA=true: A is c-major (b,c,n); staging does the n<->c transpose in LDS
//   with a row-XOR column swizzle (col ^ (row&56)).
// flags==0: bf16 store (n-major).  flags==1: fp32 write out = acc+bias+y
// (residual from ycr, c-major bf16).  flags==2: bf16 store c-major (ushort4).
// ---------------------------------------------------------------------------
template<bool CMA>
__device__ __forceinline__ void gemm_body(
    const ushort* __restrict__ A, const ushort* __restrict__ Wb,
    const float* __restrict__ bias, const ushort* __restrict__ ycr,
    void* __restrict__ Cd, int flags, int bx, int by)
{
  __shared__ ushort As[128][72];
  __shared__ ushort Ws[64][72];
  const int tid = threadIdx.x;
  const int w = tid >> 6, lane = tid & 63;
  const int l15 = lane & 15, l16 = lane >> 4;
  const int wm = w >> 1, wn = w & 1;
  const int row0 = bx * 128, col0 = by * 64;
  const int btok = row0 >> 10;           // batch index
  const int ntok0 = row0 & 1023;
  const int ra = tid >> 3, sa8 = (tid & 7) * 8;   // staging coords
  const int g = tid & 15, u4 = (tid >> 4) * 4;     // CMA staging coords
  const int colu = u4 ^ ((g & 7) << 3);
  float4v acc[4][2];
#pragma unroll
  for (int i = 0; i < 4; ++i)
#pragma unroll
    for (int j = 0; j < 2; ++j) acc[i][j] = (float4v){0.f, 0.f, 0.f, 0.f};

  uint4 a0, a1, a2, a3, w0, w1;
#define GLOAD(KT) do { \
    if (CMA) { \
      const long ab = ((long)(btok * CDIM + (KT) + u4)) * 1024 + ntok0 + g * 8; \
      a0 = *(const uint4*)&A[ab + 0 * 1024]; \
      a1 = *(const uint4*)&A[ab + 1 * 1024]; \
      a2 = *(const uint4*)&A[ab + 2 * 1024]; \
      a3 = *(const uint4*)&A[ab + 3 * 1024]; \
    } else { \
      const long ab = (long)(row0 + ra) * CDIM + (KT) + sa8; \
      a0 = *(const uint4*)&A[ab + (long)0 * 32 * CDIM]; \
      a1 = *(const uint4*)&A[ab + (long)1 * 32 * CDIM]; \
      a2 = *(const uint4*)&A[ab + (long)2 * 32 * CDIM]; \
      a3 = *(const uint4*)&A[ab + (long)3 * 32 * CDIM]; \
    } \
    const long wb = (long)(col0 + ra) * CDIM + (KT) + sa8; \
    w0 = *(const uint4*)&Wb[wb]; \
    w1 = *(const uint4*)&Wb[wb + (long)32 * CDIM]; } while (0)

#define LWRITE() do { \
    if (CMA) { \
      const ushort* s0 = (const ushort*)&a0; \
      const ushort* s1 = (const ushort*)&a1; \
      const ushort* s2 = (const ushort*)&a2; \
      const ushort* s3 = (const ushort*)&a3; \
      _Pragma("unroll") \
      for (int i = 0; i < 8; ++i) { \
        uint2 wv; \
        wv.x = (unsigned)s0[i] | ((unsigned)s1[i] << 16); \
        wv.y = (unsigned)s2[i] | ((unsigned)s3[i] << 16); \
        *(uint2*)&As[g * 8 + i][colu] = wv; \
      } \
    } else { \
      *(uint4*)&As[ra +  0][sa8] = a0; \
      *(uint4*)&As[ra + 32][sa8] = a1; \
      *(uint4*)&As[ra + 64][sa8] = a2; \
      *(uint4*)&As[ra + 96][sa8] = a3; \
    } \
    *(uint4*)&Ws[ra][sa8] = w0; \
    *(uint4*)&Ws[ra + 32][sa8] = w1; } while (0)

  GLOAD(0);
  for (int kt = 0; kt < CDIM; kt += 64) {
    LWRITE();
    __syncthreads();
    if (kt + 64 < CDIM) GLOAD(kt + 64);  // hidden under compute
#pragma unroll
    for (int s = 0; s < 2; ++s) {
      short8v a[4], bfr[2];
#pragma unroll
      for (int i = 0; i < 4; ++i) {
        int arow = wm * 64 + i * 16 + l15;
        int acol = s * 32 + l16 * 8;
        if (CMA) acol ^= (arow & 56);
        a[i] = *(const short8v*)&As[arow][acol];
      }
#pragma unroll
      for (int j = 0; j < 2; ++j)
        bfr[j] = *(const short8v*)&Ws[wn * 32 + j * 16 + l15][s * 32 + l16 * 8];
#pragma unroll
      for (int i = 0; i < 4; ++i)
#pragma unroll
        for (int j = 0; j < 2; ++j)
          acc[i][j] = __builtin_amdgcn_mfma_f32_16x16x32_bf16(a[i], bfr[j], acc[i][j], 0, 0, 0);
    }
    if (kt + 64 < CDIM) __syncthreads();
  }
#undef GLOAD
#undef LWRITE
#pragma unroll
  for (int i = 0; i < 4; ++i)
#pragma unroll
    for (int j = 0; j < 2; ++j) {
      int col = col0 + wn * 32 + j * 16 + l15;
      int rbase = row0 + wm * 64 + i * 16 + l16 * 4;
      int ntok = ntok0 + wm * 64 + i * 16 + l16 * 4;
      if (flags == 2) {
        ushort4 pk = { f2bf(acc[i][j][0]), f2bf(acc[i][j][1]),
                       f2bf(acc[i][j][2]), f2bf(acc[i][j][3]) };
        *(ushort4*)&((ushort*)Cd)[((long)(btok * CDIM + col)) * 1024 + ntok] = pk;
      } else if (flags == 1) {
        ushort4 yv = *(const ushort4*)&ycr[((long)(btok * CDIM + col)) * 1024 + ntok];
        float bcol = bias[col];
        float* op = (float*)Cd;
        op[(long)(rbase + 0) * CDIM + col] = acc[i][j][0] + bcol + bf2f(yv.x);
        op[(long)(rbase + 1) * CDIM + col] = acc[i][j][1] + bcol + bf2f(yv.y);
        op[(long)(rbase + 2) * CDIM + col] = acc[i][j][2] + bcol + bf2f(yv.z);
        op[(long)(rbase + 3) * CDIM + col] = acc[i][j][3] + bcol + bf2f(yv.w);
      } else {
#pragma unroll
        for (int r = 0; r < 4; ++r)
          ((ushort*)Cd)[(long)(rbase + r) * CDIM + col] = f2bf(acc[i][j][r]);
      }
    }
}

// fused q/k/v projection GEMMs reading c-major conv outputs directly.
// z==2 (V) writes its output c-major.
__global__ __launch_bounds__(256) void gemm_qkv_k(
    const ushort* __restrict__ qc, const ushort* __restrict__ kc, const ushort* __restrict__ vc,
    const ushort* __restrict__ wqb, const ushort* __restrict__ wkb, const ushort* __restrict__ wvb,
    ushort* __restrict__ q1, ushort* __restrict__ k1, ushort* __restrict__ vtc)
{
  const int z = blockIdx.z;
  const ushort* A  = z == 0 ? qc  : z == 1 ? kc  : vc;
  const ushort* Wb = z == 0 ? wqb : z == 1 ? wkb : wvb;
  ushort*       C  = z == 0 ? q1  : z == 1 ? k1  : vtc;
  gemm_body<true>(A, Wb, nullptr, nullptr, C, z == 2 ? 2 : 0, blockIdx.x, blockIdx.y);
}

// final projection: out = A@wo^T + bo + x_fft (residual from yc)
__global__ __launch_bounds__(256) void gemm_out_k(
    const ushort* __restrict__ A, const ushort* __restrict__ Wb,
    const float* __restrict__ bias, const ushort* __restrict__ ycr,
    float* __restrict__ Cd)
{
  gemm_body<false>(A, Wb, bias, ycr, Cd, 1, blockIdx.x, blockIdx.y);
}

// ---------------------------------------------------------------------------
// Kernel 4: MFMA flash attention, TWO 64-row q-tiles per block (grid 64x8).
// K/V staging + barriers shared by 2x compute.  Swapped QK^T, cvt_pk P pack,
// no-max softmax, ones-MFMA row sums, Q direct from global, T14-lite reg
// prefetch of the next K/V tile.
// ---------------------------------------------------------------------------
__global__ __launch_bounds__(256) void attn_mfma_k(
    const ushort* __restrict__ q1, const ushort* __restrict__ k1,
    const ushort* __restrict__ vt, ushort* __restrict__ ao)
{
  const int bh = blockIdx.x, qt2 = blockIdx.y;
  const int b = bh >> 3, h = bh & 7;
  const int tid = threadIdx.x;
  const int w = tid >> 6, lane = tid & 63;
  const int l15 = lane & 15, l16 = lane >> 4;
  __shared__ ushort Ks[64][72], Vs[48][72], Ps[128][72];
  const float scale = 0.051031036307982884f;  // 384^-0.5
  const long base = (long)b * NPIX * CDIM + h * 48;
  const long vbase = (long)bh * 48 * NPIX;

  // per-thread staging descriptors (scalars -> no scratch).
  const int i0 = tid, i1 = tid + 256, i2 = tid + 512;
  const int r0 = i0 / 6, s0 = i0 - r0 * 6;
  const ushort* gp0 = k1 + base + (long)r0 * CDIM + s0 * 8;
  const long st0 = (long)64 * CDIM;
  ushort* lp0 = &Ks[r0][s0 * 8];
  const ushort* gp1; long st1; ushort* lp1;
  if (i1 < 384) {
    int r = i1 / 6, s = i1 - r * 6;
    gp1 = k1 + base + (long)r * CDIM + s * 8; st1 = (long)64 * CDIM; lp1 = &Ks[r][s * 8];
  } else {
    int j = i1 - 384, d = j >> 3, s = j & 7;
    gp1 = vt + vbase + (long)d * NPIX + s * 8; st1 = 64; lp1 = &Vs[d][s * 8];
  }
  const int j2 = i2 - 384, d2 = j2 >> 3, s2 = j2 & 7;
  const ushort* gp2 = vt + vbase + (long)d2 * NPIX + s2 * 8;
  const long st2 = 64;
  ushort* lp2 = &Vs[d2][s2 * 8];

  // zero K pad (cols 48..63), persists across iterations
  if (tid < 128) {
    uint4 z4 = {0u, 0u, 0u, 0u};
    int r = tid >> 1, s = tid & 1;
    *(uint4*)&Ks[r][48 + s * 8] = z4;
  }
  // Q fragments for both q-tile halves, direct from global
  const long qrowA = base + (long)(qt2 * 128 + w * 16 + l15) * CDIM;
  const long qrowB = qrowA + (long)64 * CDIM;
  short8v qa0A = *(const short8v*)&q1[qrowA + l16 * 8];
  short8v qa0B = *(const short8v*)&q1[qrowB + l16 * 8];
  short8v qa1A, qa1B;
  {
    short8v qz = {};
    short8v qvA = *(const short8v*)&q1[qrowA + ((l16 < 2) ? 32 + l16 * 8 : 0)];
    short8v qvB = *(const short8v*)&q1[qrowB + ((l16 < 2) ? 32 + l16 * 8 : 0)];
    qa1A = (l16 < 2) ? qvA : qz;
    qa1B = (l16 < 2) ? qvB : qz;
  }

  float lrunA[4] = {0.f, 0.f, 0.f, 0.f}, lrunB[4] = {0.f, 0.f, 0.f, 0.f};
  float4v accOA[3], accOB[3];
#pragma unroll
  for (int fd = 0; fd < 3; ++fd) {
    accOA[fd] = (float4v){0.f, 0.f, 0.f, 0.f};
    accOB[fd] = (float4v){0.f, 0.f, 0.f, 0.f};
  }
  short8v onesb;
#pragma unroll
  for (int j = 0; j < 8; ++j) onesb[j] = (short)0x3F80;  // bf16 1.0

  uint4 t0 = *(const uint4*)gp0;          // tile 0 loads
  uint4 t1 = *(const uint4*)gp1;
  uint4 t2 = *(const uint4*)gp2;

  for (int kt = 0; kt < 16; ++kt) {
    *(uint4*)lp0 = t0;
    *(uint4*)lp1 = t1;
    *(uint4*)lp2 = t2;
    __syncthreads();
    if (kt + 1 < 16) {                    // issue loads for t+1 under compute
      t0 = *(const uint4*)(gp0 + (long)(kt + 1) * st0);
      t1 = *(const uint4*)(gp1 + (long)(kt + 1) * st1);
      t2 = *(const uint4*)(gp2 + (long)(kt + 1) * st2);
    }
    // swapped QK^T for both halves: K frags loaded once
    float4v saccA[4], saccB[4];
#pragma unroll
    for (int fc = 0; fc < 4; ++fc) {
      short8v kb0 = *(const short8v*)&Ks[fc * 16 + l15][l16 * 8];
      short8v kb1 = *(const short8v*)&Ks[fc * 16 + l15][32 + l16 * 8];
      saccA[fc] = (float4v){0.f, 0.f, 0.f, 0.f};
      saccA[fc] = __builtin_amdgcn_mfma_f32_16x16x32_bf16(kb0, qa0A, saccA[fc], 0, 0, 0);
      saccA[fc] = __builtin_amdgcn_mfma_f32_16x16x32_bf16(kb1, qa1A, saccA[fc], 0, 0, 0);
      saccB[fc] = (float4v){0.f, 0.f, 0.f, 0.f};
      saccB[fc] = __builtin_amdgcn_mfma_f32_16x16x32_bf16(kb0, qa0B, saccB[fc], 0, 0, 0);
      saccB[fc] = __builtin_amdgcn_mfma_f32_16x16x32_bf16(kb1, qa1B, saccB[fc], 0, 0, 0);
    }
    // P = exp(S*scale); pack pairs -> dword stores (rows wave-private)
    unsigned* prowA = (unsigned*)&Ps[w * 16 + l15][0];
    unsigned* prowB = (unsigned*)&Ps[64 + w * 16 + l15][0];
#pragma unroll
    for (int fc = 0; fc < 4; ++fc) {
      float a0f = __expf(saccA[fc][0] * scale), a1f = __expf(saccA[fc][1] * scale);
      float a2f = __expf(saccA[fc][2] * scale), a3f = __expf(saccA[fc][3] * scale);
      __hip_bfloat162 dA01 = __float22bfloat162_rn(make_float2(a0f, a1f));
      __hip_bfloat162 dA23 = __float22bfloat162_rn(make_float2(a2f, a3f));
      prowA[fc * 8 + l16 * 2 + 0] = *(unsigned*)&dA01;
      prowA[fc * 8 + l16 * 2 + 1] = *(unsigned*)&dA23;
      float b0f = __expf(saccB[fc][0] * scale), b1f = __expf(saccB[fc][1] * scale);
      float b2f = __expf(saccB[fc][2] * scale), b3f = __expf(saccB[fc][3] * scale);
      __hip_bfloat162 dB01 = __float22bfloat162_rn(make_float2(b0f, b1f));
      __hip_bfloat162 dB23 = __float22bfloat162_rn(make_float2(b2f, b3f));
      prowB[fc * 8 + l16 * 2 + 0] = *(unsigned*)&dB01;
      prowB[fc * 8 + l16 * 2 + 1] = *(unsigned*)&dB23;
    }
    asm volatile("s_waitcnt lgkmcnt(0)" ::: "memory");
    __builtin_amdgcn_sched_barrier(0);
    short8v pa0A = *(const short8v*)&Ps[w * 16 + l15][l16 * 8];
    short8v pa1A = *(const short8v*)&Ps[w * 16 + l15][32 + l16 * 8];
    short8v pa0B = *(const short8v*)&Ps[64 + w * 16 + l15][l16 * 8];
    short8v pa1B = *(const short8v*)&Ps[64 + w * 16 + l15][32 + l16 * 8];
    // row sums via ones-MFMA
    float4v srA = (float4v){0.f, 0.f, 0.f, 0.f};
    srA = __builtin_amdgcn_mfma_f32_16x16x32_bf16(pa0A, onesb, srA, 0, 0, 0);
    srA = __builtin_amdgcn_mfma_f32_16x16x32_bf16(pa1A, onesb, srA, 0, 0, 0);
    float4v srB = (float4v){0.f, 0.f, 0.f, 0.f};
    srB = __builtin_amdgcn_mfma_f32_16x16x32_bf16(pa0B, onesb, srB, 0, 0, 0);
    srB = __builtin_amdgcn_mfma_f32_16x16x32_bf16(pa1B, onesb, srB, 0, 0, 0);
#pragma unroll
    for (int r = 0; r < 4; ++r) { lrunA[r] += srA[r]; lrunB[r] += srB[r]; }
    // PV for both halves; V frags loaded once
#pragma unroll
    for (int fd = 0; fd < 3; ++fd) {
      short8v vb0 = *(const short8v*)&Vs[fd * 16 + l15][l16 * 8];
      short8v vb1 = *(const short8v*)&Vs[fd * 16 + l15][32 + l16 * 8];
      accOA[fd] = __builtin_amdgcn_mfma_f32_16x16x32_bf16(pa0A, vb0, accOA[fd], 0, 0, 0);
      accOA[fd] = __builtin_amdgcn_mfma_f32_16x16x32_bf16(pa1A, vb1, accOA[fd], 0, 0, 0);
      accOB[fd] = __builtin_amdgcn_mfma_f32_16x16x32_bf16(pa0B, vb0, accOB[fd], 0, 0, 0);
      accOB[fd] = __builtin_amdgcn_mfma_f32_16x16x32_bf16(pa1B, vb1, accOB[fd], 0, 0, 0);
    }
    __syncthreads();                      // compute done; LDS free for t+1
  }
  float invA[4], invB[4];
#pragma unroll
  for (int r = 0; r < 4; ++r) { invA[r] = 1.f / lrunA[r]; invB[r] = 1.f / lrunB[r]; }
#pragma unroll
  for (int fd = 0; fd < 3; ++fd)
#pragma unroll
    for (int r = 0; r < 4; ++r) {
      int qrA = qt2 * 128 + w * 16 + l16 * 4 + r;
      ao[base + (long)qrA * CDIM + fd * 16 + l15] = f2bf(accOA[fd][r] * invA[r]);
      ao[base + (long)(qrA + 64) * CDIM + fd * 16 + l15] = f2bf(accOB[fd][r] * invB[r]);
    }
}

// ---------------------------------------------------------------------------
extern "C" void kernel_launch(void* const* d_in, const int* in_sizes, int n_in,
                              void* d_out, int out_size, void* d_ws, size_t ws_size,
                              hipStream_t stream) {
  const float* x   = (const float*)d_in[0];
  const float* cw  = (const float*)d_in[1];
  const float* dwq = (const float*)d_in[2];
  const float* dwk = (const float*)d_in[3];
  const float* dwv = (const float*)d_in[4];
  const float* gq  = (const float*)d_in[5];
  const float* bq  = (const float*)d_in[6];
  const float* mq  = (const float*)d_in[7];
  const float* vq  = (const float*)d_in[8];
  const float* gk  = (const float*)d_in[9];
  const float* bk  = (const float*)d_in[10];
  const float* mk  = (const float*)d_in[11];
  const float* vk  = (const float*)d_in[12];
  const float* gv  = (const float*)d_in[13];
  const float* bv  = (const float*)d_in[14];
  const float* mv  = (const float*)d_in[15];
  const float* vv  = (const float*)d_in[16];
  const float* wq  = (const float*)d_in[17];
  const float* wk  = (const float*)d_in[18];
  const float* wv  = (const float*)d_in[19];
  const float* wo  = (const float*)d_in[20];
  const float* bo  = (const float*)d_in[21];
  float* out = (float*)d_out;

  char* wsb = (char*)d_ws;
  const size_t H = (size_t)NB * NPIX * CDIM * 2;        // 6,291,456 B
  // slot plan (each H):
  // S0: xc -> vtc | S1: yc | S2: qc -> ao | S3: kc | S4: vc
  // S5: q1 | S6: k1 | S7: weights + tbl
  ushort* xcp = (ushort*)(wsb + 0 * H);
  ushort* vtc = (ushort*)(wsb + 0 * H);
  ushort* yc  = (ushort*)(wsb + 1 * H);
  ushort* qc  = (ushort*)(wsb + 2 * H);
  ushort* ao  = (ushort*)(wsb + 2 * H);
  ushort* kc  = (ushort*)(wsb + 3 * H);
  ushort* vc  = (ushort*)(wsb + 4 * H);
  ushort* q1  = (ushort*)(wsb + 5 * H);
  ushort* k1  = (ushort*)(wsb + 6 * H);
  ushort* wqb = (ushort*)(wsb + 7 * H);
  ushort* wkb = wqb + CDIM * CDIM;
  ushort* wvb = wkb + CDIM * CDIM;
  ushort* wob = wvb + CDIM * CDIM;
  ushort* tbl = wob + CDIM * CDIM;                      // 5*1024 ushorts

  prep_k<<<dim3(932), 256, 0, stream>>>(tbl, wq, wk, wv, wo,
      wqb, wkb, wvb, wob, x, xcp);
  fft_conv_k<<<dim3(NB * CDIM), 256, 0, stream>>>(xcp, cw, tbl, dwq, dwk, dwv,
      gq, bq, mq, vq, gk, bk, mk, vk, gv, bv, mv, vv, yc, qc, kc, vc);
  gemm_qkv_k<<<dim3(64, 6, 3), 256, 0, stream>>>(qc, kc, vc, wqb, wkb, wvb, q1, k1, vtc);
  attn_mfma_k<<<dim3(64, 8), 256, 0, stream>>>(q1, k1, vtc, ao);
  gemm_out_k<<<dim3(64, 6), 256, 0, stream>>>(ao, wob, bo, yc, out);
}